// Round 2
// baseline (564.834 us; speedup 1.0000x reference)
//
#include <hip/hip_runtime.h>
#include <hip/hip_bf16.h>
#include <stdint.h>

#define BATCH 32
#define NPART 10
#define BP_TOT 320
#define DM 256
#define FF 1024
#define OD 32
#define SL 512

// ---------------- threefry2x32 (JAX-exact, key = (0, 42)) ----------------
__device__ __forceinline__ uint32_t rotl32(uint32_t x, uint32_t r) {
    return (x << r) | (x >> (32u - r));
}

__device__ __forceinline__ void threefry2x32(uint32_t k0, uint32_t k1,
                                             uint32_t x0, uint32_t x1,
                                             uint32_t& o0, uint32_t& o1) {
    uint32_t k2 = k0 ^ k1 ^ 0x1BD11BDAu;
    uint32_t x = x0 + k0, y = x1 + k1;
#define TFR(r) { x += y; y = rotl32(y, r); y ^= x; }
    TFR(13u) TFR(15u) TFR(26u) TFR(6u)
    x += k1; y += k2 + 1u;
    TFR(17u) TFR(29u) TFR(16u) TFR(24u)
    x += k2; y += k0 + 2u;
    TFR(13u) TFR(15u) TFR(26u) TFR(6u)
    x += k0; y += k1 + 3u;
    TFR(17u) TFR(29u) TFR(16u) TFR(24u)
    x += k1; y += k2 + 4u;
    TFR(13u) TFR(15u) TFR(26u) TFR(6u)
    x += k2; y += k0 + 5u;
#undef TFR
    o0 = x; o1 = y;
}

// JAX PARTITIONABLE-mode random bits (jax_threefry_partitionable=True,
// default in modern JAX): element m of an N-element u32 draw uses
// counter (hi32(m), lo32(m)) = (0, m) and returns bits1 ^ bits2.
__device__ __forceinline__ float jax_gumbel_part(uint32_t m) {
    const float TINY = 1.17549435e-38f;
    uint32_t o0, o1;
    threefry2x32(0u, 42u, 0u, m, o0, o1);
    uint32_t bits = o0 ^ o1;
    uint32_t fb = (bits >> 9) | 0x3f800000u;
    float f = __uint_as_float(fb) - 1.0f;
    // uniform(minval=tiny, maxval=1): f*(1-tiny)+tiny == f+tiny in fp32, clamp
    float u = fmaxf(TINY, f + TINY);
    return -logf(-logf(u));
}

// ---------------- Kernel A: fused per-particle forward ----------------
__global__ __launch_bounds__(256) void fwd_kernel(
    const float* __restrict__ x,
    const float* __restrict__ Kin, const float* __restrict__ Vin,
    const float* __restrict__ nq, const float* __restrict__ nk,
    const float* __restrict__ nv, const float* __restrict__ nz,
    const float* __restrict__ wq_w, const float* __restrict__ wq_b,
    const float* __restrict__ wk_w, const float* __restrict__ wk_b,
    const float* __restrict__ wv_w, const float* __restrict__ wv_b,
    const float* __restrict__ wz_w, const float* __restrict__ wz_b,
    const float* __restrict__ ln1_g, const float* __restrict__ ln1_b,
    const float* __restrict__ w1, const float* __restrict__ b1,
    const float* __restrict__ w2, const float* __restrict__ b2,
    const float* __restrict__ ln2_g, const float* __restrict__ ln2_b,
    const int* __restrict__ t_ptr,
    float* __restrict__ r_out, float* __restrict__ attn_out,
    float* __restrict__ knew, float* __restrict__ vnew)
{
    const int bp   = blockIdx.x;     // 0..319  (b*10+p)
    const int tid  = threadIdx.x;    // 0..255
    const int lane = tid & 63;
    const int wave = tid >> 6;
    const int t    = *t_ptr;
    const float sq = 0.31622776601683794f;  // sqrt(SIGMA=0.1)

    __shared__ float xs[DM], qs[DM], ks[DM], vs[DM];
    __shared__ float att[SL];
    __shared__ float buf[DM];   // reused: z, then ln1-out
    __shared__ float hid[FF];
    __shared__ float red[8];

    xs[tid] = x[bp * DM + tid];
    __syncthreads();

    // q,k,v projections: thread tid computes output element tid of each.
    float aq = 0.f, ak = 0.f, av = 0.f;
    #pragma unroll 4
    for (int i = 0; i < DM; ++i) {
        float xi = xs[i];
        aq = fmaf(xi, wq_w[i * DM + tid], aq);
        ak = fmaf(xi, wk_w[i * DM + tid], ak);
        av = fmaf(xi, wv_w[i * DM + tid], av);
    }
    float qv = aq + wq_b[tid] + sq * nq[bp * DM + tid];
    float kv = ak + wk_b[tid] + sq * nk[bp * DM + tid];
    float vv = av + wv_b[tid] + sq * nv[bp * DM + tid];
    qs[tid] = qv; ks[tid] = kv; vs[tid] = vv;
    knew[bp * DM + tid] = kv;
    vnew[bp * DM + tid] = vv;
    __syncthreads();

    // logits[s] = q . K_new[s] / 16  — wave-cooperative, float4 coalesced
    const float* Kbp = Kin + (size_t)bp * SL * DM;
    float4 q4 = *(const float4*)&qs[lane * 4];
    for (int s = wave; s < SL; s += 4) {
        float4 k4;
        if (s == t) k4 = *(const float4*)&ks[lane * 4];
        else        k4 = *(const float4*)&Kbp[(size_t)s * DM + lane * 4];
        float acc = q4.x * k4.x + q4.y * k4.y + q4.z * k4.z + q4.w * k4.w;
        #pragma unroll
        for (int off = 32; off; off >>= 1) acc += __shfl_down(acc, off);
        if (lane == 0) att[s] = acc * 0.0625f;
    }
    __syncthreads();

    // softmax over 512
    float l0 = att[tid], l1 = att[tid + 256];
    float m = fmaxf(l0, l1);
    #pragma unroll
    for (int off = 32; off; off >>= 1) m = fmaxf(m, __shfl_down(m, off));
    if (lane == 0) red[wave] = m;
    __syncthreads();
    float gm = fmaxf(fmaxf(red[0], red[1]), fmaxf(red[2], red[3]));
    float e0 = expf(l0 - gm), e1 = expf(l1 - gm);
    float ssum = e0 + e1;
    #pragma unroll
    for (int off = 32; off; off >>= 1) ssum += __shfl_down(ssum, off);
    if (lane == 0) red[4 + wave] = ssum;
    __syncthreads();
    float inv = 1.0f / (red[4] + red[5] + red[6] + red[7]);
    float a0 = e0 * inv, a1 = e1 * inv;
    att[tid] = a0; att[tid + 256] = a1;
    attn_out[(size_t)bp * SL + tid]       = a0;
    attn_out[(size_t)bp * SL + tid + 256] = a1;
    __syncthreads();

    // z[d] = sum_s att[s] * V_new[s][d]  — coalesced across threads
    const float* Vbp = Vin + (size_t)bp * SL * DM;
    float zacc = 0.f;
    #pragma unroll 4
    for (int s = 0; s < SL; ++s) {
        float a  = att[s];
        float vd = (s == t) ? vs[tid] : Vbp[(size_t)s * DM + tid];
        zacc = fmaf(a, vd, zacc);
    }
    buf[tid] = zacc;
    __syncthreads();

    // z projection + noise + residual
    float az = 0.f;
    #pragma unroll 4
    for (int i = 0; i < DM; ++i) az = fmaf(buf[i], wz_w[i * DM + tid], az);
    float h = az + wz_b[tid] + sq * nz[bp * DM + tid] + xs[tid];

    // layernorm 1
    float s1 = h;
    #pragma unroll
    for (int off = 32; off; off >>= 1) s1 += __shfl_down(s1, off);
    __syncthreads();
    if (lane == 0) red[wave] = s1;
    __syncthreads();
    float mu = (red[0] + red[1] + red[2] + red[3]) * (1.0f / DM);
    float dv = h - mu;
    float s2 = dv * dv;
    #pragma unroll
    for (int off = 32; off; off >>= 1) s2 += __shfl_down(s2, off);
    if (lane == 0) red[4 + wave] = s2;
    __syncthreads();
    float var = (red[4] + red[5] + red[6] + red[7]) * (1.0f / DM);
    float o = dv * rsqrtf(var + 1e-6f) * ln1_g[tid] + ln1_b[tid];
    __syncthreads();
    buf[tid] = o;
    __syncthreads();

    // FFN layer 1 (256 -> 1024) + relu
    float h0 = 0.f, h1 = 0.f, h2 = 0.f, h3 = 0.f;
    #pragma unroll 2
    for (int i = 0; i < DM; ++i) {
        float oi = buf[i];
        h0 = fmaf(oi, w1[i * FF + tid],       h0);
        h1 = fmaf(oi, w1[i * FF + tid + 256], h1);
        h2 = fmaf(oi, w1[i * FF + tid + 512], h2);
        h3 = fmaf(oi, w1[i * FF + tid + 768], h3);
    }
    hid[tid]       = fmaxf(h0 + b1[tid],       0.f);
    hid[tid + 256] = fmaxf(h1 + b1[tid + 256], 0.f);
    hid[tid + 512] = fmaxf(h2 + b1[tid + 512], 0.f);
    hid[tid + 768] = fmaxf(h3 + b1[tid + 768], 0.f);
    __syncthreads();

    // FFN layer 2 (1024 -> 256) + residual
    float ar = 0.f;
    #pragma unroll 4
    for (int i = 0; i < FF; ++i) ar = fmaf(hid[i], w2[i * DM + tid], ar);
    float rr = ar + b2[tid] + o;

    // layernorm 2
    float t1 = rr;
    #pragma unroll
    for (int off = 32; off; off >>= 1) t1 += __shfl_down(t1, off);
    __syncthreads();
    if (lane == 0) red[wave] = t1;
    __syncthreads();
    float mu2 = (red[0] + red[1] + red[2] + red[3]) * (1.0f / DM);
    float dv2 = rr - mu2;
    float t2 = dv2 * dv2;
    #pragma unroll
    for (int off = 32; off; off >>= 1) t2 += __shfl_down(t2, off);
    if (lane == 0) red[4 + wave] = t2;
    __syncthreads();
    float var2 = (red[4] + red[5] + red[6] + red[7]) * (1.0f / DM);
    float rf = dv2 * rsqrtf(var2 + 1e-6f) * ln2_g[tid] + ln2_b[tid];
    r_out[bp * DM + tid] = rf;
}

// ---------------- Kernel B: particle weights + resample indices ----------------
__global__ __launch_bounds__(320) void weights_kernel(
    const float* __restrict__ r, const float* __restrict__ y,
    const float* __restrict__ out_w, const float* __restrict__ out_b,
    float* __restrict__ w_out, int* __restrict__ i_t)
{
    const int b   = blockIdx.x;    // 0..31
    const int tid = threadIdx.x;   // 0..319
    const int p   = tid >> 5;      // 0..9
    const int j   = tid & 31;      // 0..31

    __shared__ float sred[NPART];
    __shared__ float es[NPART];
    __shared__ float pe[NPART];
    __shared__ float wsm[NPART];

    // predictions[j] = r[b,p,:] . out_w[:,j] + out_b[j];  mu = y - pred
    const float* rrow = r + (size_t)(b * NPART + p) * DM;
    float acc = 0.f;
    #pragma unroll 4
    for (int i = 0; i < DM; ++i) acc = fmaf(rrow[i], out_w[i * OD + j], acc);
    float pred = acc + out_b[j];
    float muv  = y[(size_t)(b * NPART + p) * OD + j] - pred;
    float s    = muv * muv;
    #pragma unroll
    for (int off = 16; off; off >>= 1) s += __shfl_down(s, off, 32);
    if (j == 0) sred[p] = s;   // sum mu^2 ; log_w = -s/(2*0.5) = -s
    __syncthreads();

    // w = softmax(exp(log_w)) over particles
    if (tid < NPART) es[tid] = expf(-sred[tid]);
    __syncthreads();
    if (tid < NPART) {
        float mx = es[0];
        #pragma unroll
        for (int i = 1; i < NPART; ++i) mx = fmaxf(mx, es[i]);
        pe[tid] = expf(es[tid] - mx);
    }
    __syncthreads();
    if (tid < NPART) {
        float sum = 0.f;
        #pragma unroll
        for (int i = 0; i < NPART; ++i) sum += pe[i];
        float wv = pe[tid] / sum;
        w_out[b * NPART + tid] = wv;
        wsm[tid] = wv;
    }
    __syncthreads();

    // i_t[b,p] = argmax_j( gumbel[b,p,j] + w[b,j] ), first max (JAX argmax)
    if (tid < NPART) {
        int pp = tid;
        int best = 0;
        float bests = -3.402823466e+38f;
        #pragma unroll
        for (int jj = 0; jj < NPART; ++jj) {
            uint32_t m = (uint32_t)(b * 100 + pp * 10 + jj);
            float score = jax_gumbel_part(m) + wsm[jj];
            if (score > bests) { bests = score; best = jj; }
        }
        i_t[b * NPART + pp] = best;
    }
}

// ---------------- Kernel C: resample gather-copy of K, V, R ----------------
__global__ __launch_bounds__(256) void resample_kernel(
    const float* __restrict__ Kin, const float* __restrict__ Vin,
    const float* __restrict__ Rin,
    const float* __restrict__ knew, const float* __restrict__ vnew,
    const float* __restrict__ rnew,
    const int* __restrict__ i_t, const int* __restrict__ t_ptr,
    float* __restrict__ Kout, float* __restrict__ Vout, float* __restrict__ Rout)
{
    const int t      = *t_ptr;
    const int tensor = blockIdx.y;          // 0=K 1=V 2=R
    const int tid    = threadIdx.x;
    size_t idx  = (size_t)blockIdx.x * 256 + tid;
    int lane4 = (int)(idx & 63);            // float4 slot within row
    int row   = (int)(idx >> 6);            // 0..163839
    int bpi   = row >> 9;                   // 0..319
    int s     = row & 511;
    int b     = bpi / NPART;
    int p     = bpi - b * NPART;
    int srcp  = (s <= t) ? i_t[bpi] : p;
    int src_bpi = b * NPART + srcp;

    const float* src;
    if (s == t) {
        const float* nb = (tensor == 0) ? knew : (tensor == 1) ? vnew : rnew;
        src = nb + (size_t)src_bpi * DM;
    } else {
        const float* base = (tensor == 0) ? Kin : (tensor == 1) ? Vin : Rin;
        src = base + ((size_t)src_bpi * SL + s) * DM;
    }
    float* outb = (tensor == 0) ? Kout : (tensor == 1) ? Vout : Rout;
    float4 v4 = *(const float4*)(src + (size_t)lane4 * 4);
    *(float4*)(outb + (size_t)row * DM + (size_t)lane4 * 4) = v4;
}

// ---------------- launch ----------------
extern "C" void kernel_launch(void* const* d_in, const int* in_sizes, int n_in,
                              void* d_out, int out_size, void* d_ws, size_t ws_size,
                              hipStream_t stream) {
    const float* x    = (const float*)d_in[0];
    const float* y    = (const float*)d_in[1];
    const float* Kin  = (const float*)d_in[2];
    const float* Vin  = (const float*)d_in[3];
    const float* Rin  = (const float*)d_in[4];
    const float* nq   = (const float*)d_in[5];
    const float* nk   = (const float*)d_in[6];
    const float* nv   = (const float*)d_in[7];
    const float* nz   = (const float*)d_in[8];
    const int*   tptr = (const int*)d_in[9];
    const float* wq_w = (const float*)d_in[10];
    const float* wq_b = (const float*)d_in[11];
    const float* wk_w = (const float*)d_in[12];
    const float* wk_b = (const float*)d_in[13];
    const float* wv_w = (const float*)d_in[14];
    const float* wv_b = (const float*)d_in[15];
    const float* wz_w = (const float*)d_in[16];
    const float* wz_b = (const float*)d_in[17];
    const float* ln1g = (const float*)d_in[18];
    const float* ln1b = (const float*)d_in[19];
    const float* w1   = (const float*)d_in[20];
    const float* b1   = (const float*)d_in[21];
    const float* w2   = (const float*)d_in[22];
    const float* b2   = (const float*)d_in[23];
    const float* ln2g = (const float*)d_in[24];
    const float* ln2b = (const float*)d_in[25];
    const float* outw = (const float*)d_in[26];
    const float* outb = (const float*)d_in[27];

    float* out = (float*)d_out;
    const size_t R_ELEMS    = (size_t)BP_TOT * DM;        // 81920
    const size_t ATTN_ELEMS = (size_t)BP_TOT * SL;        // 163840
    const size_t KVR_ELEMS  = (size_t)BP_TOT * SL * DM;   // 41943040
    float* r_out    = out;
    float* attn_out = out + R_ELEMS;
    float* K_out    = out + R_ELEMS + ATTN_ELEMS;
    float* V_out    = K_out + KVR_ELEMS;
    float* R_out    = V_out + KVR_ELEMS;
    float* w_out    = R_out + KVR_ELEMS;

    float* knew = (float*)d_ws;
    float* vnew = knew + R_ELEMS;
    int*   i_t  = (int*)(vnew + R_ELEMS);

    fwd_kernel<<<BP_TOT, 256, 0, stream>>>(
        x, Kin, Vin, nq, nk, nv, nz,
        wq_w, wq_b, wk_w, wk_b, wv_w, wv_b, wz_w, wz_b,
        ln1g, ln1b, w1, b1, w2, b2, ln2g, ln2b,
        tptr, r_out, attn_out, knew, vnew);

    weights_kernel<<<BATCH, 320, 0, stream>>>(
        r_out, y, outw, outb, w_out, i_t);

    // 3 tensors x 163840 rows; 4 rows per 256-thread block
    resample_kernel<<<dim3(163840 / 4, 3), 256, 0, stream>>>(
        Kin, Vin, Rin, knew, vnew, r_out, i_t, tptr,
        K_out, V_out, R_out);
}

// Round 3
// 407.116 us; speedup vs baseline: 1.3874x; 1.3874x over previous
//
#include <hip/hip_runtime.h>
#include <hip/hip_bf16.h>
#include <stdint.h>

#define BATCH 32
#define NPART 10
#define BP_TOT 320
#define DM 256
#define FF 1024
#define OD 32
#define SL 512

// ---------------- threefry2x32 (JAX-exact, key = (0, 42)) ----------------
__device__ __forceinline__ uint32_t rotl32(uint32_t x, uint32_t r) {
    return (x << r) | (x >> (32u - r));
}

__device__ __forceinline__ void threefry2x32(uint32_t k0, uint32_t k1,
                                             uint32_t x0, uint32_t x1,
                                             uint32_t& o0, uint32_t& o1) {
    uint32_t k2 = k0 ^ k1 ^ 0x1BD11BDAu;
    uint32_t x = x0 + k0, y = x1 + k1;
#define TFR(r) { x += y; y = rotl32(y, r); y ^= x; }
    TFR(13u) TFR(15u) TFR(26u) TFR(6u)
    x += k1; y += k2 + 1u;
    TFR(17u) TFR(29u) TFR(16u) TFR(24u)
    x += k2; y += k0 + 2u;
    TFR(13u) TFR(15u) TFR(26u) TFR(6u)
    x += k0; y += k1 + 3u;
    TFR(17u) TFR(29u) TFR(16u) TFR(24u)
    x += k1; y += k2 + 4u;
    TFR(13u) TFR(15u) TFR(26u) TFR(6u)
    x += k2; y += k0 + 5u;
#undef TFR
    o0 = x; o1 = y;
}

// JAX partitionable-mode random bits: element m uses counter (0, m), bits = o0 ^ o1.
__device__ __forceinline__ float jax_gumbel_part(uint32_t m) {
    const float TINY = 1.17549435e-38f;
    uint32_t o0, o1;
    threefry2x32(0u, 42u, 0u, m, o0, o1);
    uint32_t bits = o0 ^ o1;
    uint32_t fb = (bits >> 9) | 0x3f800000u;
    float f = __uint_as_float(fb) - 1.0f;
    float u = fmaxf(TINY, f + TINY);
    return -logf(-logf(u));
}

// ---------------- Kernel A: fused per-particle forward (16 waves) ----------------
__global__ __launch_bounds__(1024) void fwd_kernel(
    const float* __restrict__ x,
    const float* __restrict__ Kin, const float* __restrict__ Vin,
    const float* __restrict__ nq, const float* __restrict__ nk,
    const float* __restrict__ nv, const float* __restrict__ nz,
    const float* __restrict__ wq_w, const float* __restrict__ wq_b,
    const float* __restrict__ wk_w, const float* __restrict__ wk_b,
    const float* __restrict__ wv_w, const float* __restrict__ wv_b,
    const float* __restrict__ wz_w, const float* __restrict__ wz_b,
    const float* __restrict__ ln1_g, const float* __restrict__ ln1_b,
    const float* __restrict__ w1, const float* __restrict__ b1,
    const float* __restrict__ w2, const float* __restrict__ b2,
    const float* __restrict__ ln2_g, const float* __restrict__ ln2_b,
    const int* __restrict__ t_ptr,
    float* __restrict__ r_out, float* __restrict__ attn_out,
    float* __restrict__ knew, float* __restrict__ vnew)
{
    const int bp   = blockIdx.x;     // 0..319
    const int tid  = threadIdx.x;    // 0..1023
    const int lane = tid & 63;
    const int wave = tid >> 6;       // 0..15
    const int grp  = tid >> 8;       // 0..3
    const int qtid = tid & 255;
    const int t    = *t_ptr;
    const float sq = 0.31622776601683794f;  // sqrt(0.1)

    __shared__ float xs[DM], qs[DM], ks[DM], vs[DM];
    __shared__ float att[SL];
    __shared__ float buf[DM];
    __shared__ float hid[FF];
    __shared__ float scratch[4096];   // reused: qkv partials / z partials / proj partials
    __shared__ float red[32];

    if (tid < DM) xs[tid] = x[bp * DM + tid];
    __syncthreads();

    // ---- P1: QKV projections, i-split 4 ways across groups ----
    {
        float aq = 0.f, ak = 0.f, av = 0.f;
        const int i0 = grp * 64;
        #pragma unroll 4
        for (int ii = 0; ii < 64; ++ii) {
            int i = i0 + ii;
            float xi = xs[i];
            aq = fmaf(xi, wq_w[i * DM + qtid], aq);
            ak = fmaf(xi, wk_w[i * DM + qtid], ak);
            av = fmaf(xi, wv_w[i * DM + qtid], av);
        }
        scratch[0 * 1024 + grp * 256 + qtid] = aq;
        scratch[1 * 1024 + grp * 256 + qtid] = ak;
        scratch[2 * 1024 + grp * 256 + qtid] = av;
    }
    __syncthreads();
    if (tid < 768) {
        int mat = tid >> 8, d = tid & 255;
        const float* base = scratch + mat * 1024;
        float s = base[d] + base[256 + d] + base[512 + d] + base[768 + d];
        if (mat == 0) {
            qs[d] = s + wq_b[d] + sq * nq[bp * DM + d];
        } else if (mat == 1) {
            float kv = s + wk_b[d] + sq * nk[bp * DM + d];
            ks[d] = kv; knew[bp * DM + d] = kv;
        } else {
            float vv = s + wv_b[d] + sq * nv[bp * DM + d];
            vs[d] = vv; vnew[bp * DM + d] = vv;
        }
    }
    __syncthreads();

    // ---- P2: logits, 32 rows per wave, float4 row loads ----
    {
        const float* Kbp = Kin + (size_t)bp * SL * DM;
        float4 q4 = *(const float4*)&qs[lane * 4];
        const int s0 = wave * 32;
        #pragma unroll 2
        for (int j = 0; j < 32; ++j) {
            int s = s0 + j;
            float4 k4 = (s == t) ? *(const float4*)&ks[lane * 4]
                                 : *(const float4*)&Kbp[(size_t)s * DM + lane * 4];
            float acc = q4.x * k4.x + q4.y * k4.y + q4.z * k4.z + q4.w * k4.w;
            #pragma unroll
            for (int off = 32; off; off >>= 1) acc += __shfl_down(acc, off);
            if (lane == 0) att[s] = acc * 0.0625f;
        }
    }
    __syncthreads();

    // ---- P3: softmax over 512 (waves 0..7 hold data) ----
    {
        float l = (tid < SL) ? att[tid] : -3.402823466e+38f;
        float m = l;
        #pragma unroll
        for (int off = 32; off; off >>= 1) m = fmaxf(m, __shfl_down(m, off));
        if (lane == 0) red[wave] = m;
        __syncthreads();
        float gm = red[0];
        #pragma unroll
        for (int i = 1; i < 16; ++i) gm = fmaxf(gm, red[i]);
        float e = (tid < SL) ? expf(l - gm) : 0.f;
        float ssum = e;
        #pragma unroll
        for (int off = 32; off; off >>= 1) ssum += __shfl_down(ssum, off);
        if (lane == 0) red[16 + wave] = ssum;
        __syncthreads();
        float tot = 0.f;
        #pragma unroll
        for (int i = 0; i < 16; ++i) tot += red[16 + i];
        float a = e / tot;
        if (tid < SL) {
            att[tid] = a;
            attn_out[(size_t)bp * SL + tid] = a;
        }
    }
    __syncthreads();

    // ---- P4: z = att @ V, 32 rows per wave, float4, LDS reduce ----
    {
        const float* Vbp = Vin + (size_t)bp * SL * DM;
        float4 z4 = make_float4(0.f, 0.f, 0.f, 0.f);
        const int s0 = wave * 32;
        #pragma unroll 2
        for (int j = 0; j < 32; ++j) {
            int s = s0 + j;
            float a = att[s];
            float4 v4 = (s == t) ? *(const float4*)&vs[lane * 4]
                                 : *(const float4*)&Vbp[(size_t)s * DM + lane * 4];
            z4.x = fmaf(a, v4.x, z4.x);
            z4.y = fmaf(a, v4.y, z4.y);
            z4.z = fmaf(a, v4.z, z4.z);
            z4.w = fmaf(a, v4.w, z4.w);
        }
        *(float4*)&scratch[wave * 256 + lane * 4] = z4;
    }
    __syncthreads();
    if (tid < DM) {
        float z = 0.f;
        #pragma unroll
        for (int w = 0; w < 16; ++w) z += scratch[w * 256 + tid];
        buf[tid] = z;
    }
    __syncthreads();

    // ---- P5: z projection, i-split 4 ways ----
    {
        float az = 0.f;
        const int i0 = grp * 64;
        #pragma unroll 4
        for (int ii = 0; ii < 64; ++ii) {
            int i = i0 + ii;
            az = fmaf(buf[i], wz_w[i * DM + qtid], az);
        }
        scratch[grp * 256 + qtid] = az;
    }
    __syncthreads();
    float h = 0.f;
    if (tid < DM) {
        float az = scratch[tid] + scratch[256 + tid] + scratch[512 + tid] + scratch[768 + tid];
        h = az + wz_b[tid] + sq * nz[bp * DM + tid] + xs[tid];
    }

    // ---- P6: layernorm 1 (values live in waves 0..3) ----
    float s1 = h;
    #pragma unroll
    for (int off = 32; off; off >>= 1) s1 += __shfl_down(s1, off);
    if (lane == 0) red[wave] = s1;
    __syncthreads();
    float mu = (red[0] + red[1] + red[2] + red[3]) * (1.0f / DM);
    float dv = (tid < DM) ? (h - mu) : 0.f;
    float s2 = dv * dv;
    #pragma unroll
    for (int off = 32; off; off >>= 1) s2 += __shfl_down(s2, off);
    if (lane == 0) red[16 + wave] = s2;
    __syncthreads();
    float var = (red[16] + red[17] + red[18] + red[19]) * (1.0f / DM);
    float o = 0.f;
    if (tid < DM) {
        o = dv * rsqrtf(var + 1e-6f) * ln1_g[tid] + ln1_b[tid];
        buf[tid] = o;
    }
    __syncthreads();

    // ---- P7: FFN1 (256 -> 1024), one output per thread ----
    {
        float h1 = 0.f;
        #pragma unroll 4
        for (int i = 0; i < DM; ++i) h1 = fmaf(buf[i], w1[i * FF + tid], h1);
        hid[tid] = fmaxf(h1 + b1[tid], 0.f);
    }
    __syncthreads();

    // ---- P8: FFN2 (1024 -> 256), i-split 4 ways ----
    {
        float ar = 0.f;
        const int i0 = grp * 256;
        #pragma unroll 4
        for (int ii = 0; ii < 256; ++ii) {
            int i = i0 + ii;
            ar = fmaf(hid[i], w2[i * DM + qtid], ar);
        }
        scratch[grp * 256 + qtid] = ar;
    }
    __syncthreads();
    float rr = 0.f;
    if (tid < DM) {
        rr = scratch[tid] + scratch[256 + tid] + scratch[512 + tid] + scratch[768 + tid]
           + b2[tid] + o;
    }

    // ---- P9: layernorm 2 ----
    float t1 = rr;
    #pragma unroll
    for (int off = 32; off; off >>= 1) t1 += __shfl_down(t1, off);
    if (lane == 0) red[wave] = t1;
    __syncthreads();
    float mu2 = (red[0] + red[1] + red[2] + red[3]) * (1.0f / DM);
    float dv2 = (tid < DM) ? (rr - mu2) : 0.f;
    float t2 = dv2 * dv2;
    #pragma unroll
    for (int off = 32; off; off >>= 1) t2 += __shfl_down(t2, off);
    if (lane == 0) red[16 + wave] = t2;
    __syncthreads();
    float var2 = (red[16] + red[17] + red[18] + red[19]) * (1.0f / DM);
    if (tid < DM) {
        float rf = dv2 * rsqrtf(var2 + 1e-6f) * ln2_g[tid] + ln2_b[tid];
        r_out[bp * DM + tid] = rf;
    }
}

// ---------------- Kernel B: particle weights + resample indices ----------------
__global__ __launch_bounds__(320) void weights_kernel(
    const float* __restrict__ r, const float* __restrict__ y,
    const float* __restrict__ out_w, const float* __restrict__ out_b,
    float* __restrict__ w_out, int* __restrict__ i_t)
{
    const int b   = blockIdx.x;    // 0..31
    const int tid = threadIdx.x;   // 0..319
    const int p   = tid >> 5;      // 0..9
    const int j   = tid & 31;      // 0..31

    __shared__ float sred[NPART];
    __shared__ float es[NPART];
    __shared__ float pe[NPART];
    __shared__ float wsm[NPART];

    const float* rrow = r + (size_t)(b * NPART + p) * DM;
    float acc = 0.f;
    #pragma unroll 4
    for (int i = 0; i < DM; ++i) acc = fmaf(rrow[i], out_w[i * OD + j], acc);
    float pred = acc + out_b[j];
    float muv  = y[(size_t)(b * NPART + p) * OD + j] - pred;
    float s    = muv * muv;
    #pragma unroll
    for (int off = 16; off; off >>= 1) s += __shfl_down(s, off, 32);
    if (j == 0) sred[p] = s;   // log_w = -s
    __syncthreads();

    if (tid < NPART) es[tid] = expf(-sred[tid]);
    __syncthreads();
    if (tid < NPART) {
        float mx = es[0];
        #pragma unroll
        for (int i = 1; i < NPART; ++i) mx = fmaxf(mx, es[i]);
        pe[tid] = expf(es[tid] - mx);
    }
    __syncthreads();
    if (tid < NPART) {
        float sum = 0.f;
        #pragma unroll
        for (int i = 0; i < NPART; ++i) sum += pe[i];
        float wv = pe[tid] / sum;
        w_out[b * NPART + tid] = wv;
        wsm[tid] = wv;
    }
    __syncthreads();

    if (tid < NPART) {
        int pp = tid;
        int best = 0;
        float bests = -3.402823466e+38f;
        #pragma unroll
        for (int jj = 0; jj < NPART; ++jj) {
            uint32_t m = (uint32_t)(b * 100 + pp * 10 + jj);
            float score = jax_gumbel_part(m) + wsm[jj];
            if (score > bests) { bests = score; best = jj; }
        }
        i_t[b * NPART + pp] = best;
    }
}

// ---------------- Kernel C: resample gather-copy of K, V, R ----------------
__global__ __launch_bounds__(256) void resample_kernel(
    const float* __restrict__ Kin, const float* __restrict__ Vin,
    const float* __restrict__ Rin,
    const float* __restrict__ knew, const float* __restrict__ vnew,
    const float* __restrict__ rnew,
    const int* __restrict__ i_t, const int* __restrict__ t_ptr,
    float* __restrict__ Kout, float* __restrict__ Vout, float* __restrict__ Rout)
{
    const int t      = *t_ptr;
    const int tensor = blockIdx.y;          // 0=K 1=V 2=R
    const int tid    = threadIdx.x;
    size_t idx  = (size_t)blockIdx.x * 256 + tid;
    int lane4 = (int)(idx & 63);            // float4 slot within row
    int row   = (int)(idx >> 6);            // 0..163839
    int bpi   = row >> 9;                   // 0..319
    int s     = row & 511;
    int b     = bpi / NPART;
    int p     = bpi - b * NPART;
    int srcp  = (s <= t) ? i_t[bpi] : p;
    int src_bpi = b * NPART + srcp;

    const float* src;
    if (s == t) {
        const float* nb = (tensor == 0) ? knew : (tensor == 1) ? vnew : rnew;
        src = nb + (size_t)src_bpi * DM;
    } else {
        const float* base = (tensor == 0) ? Kin : (tensor == 1) ? Vin : Rin;
        src = base + ((size_t)src_bpi * SL + s) * DM;
    }
    float* outb = (tensor == 0) ? Kout : (tensor == 1) ? Vout : Rout;
    float4 v4 = *(const float4*)(src + (size_t)lane4 * 4);
    *(float4*)(outb + (size_t)row * DM + (size_t)lane4 * 4) = v4;
}

// ---------------- launch ----------------
extern "C" void kernel_launch(void* const* d_in, const int* in_sizes, int n_in,
                              void* d_out, int out_size, void* d_ws, size_t ws_size,
                              hipStream_t stream) {
    const float* x    = (const float*)d_in[0];
    const float* y    = (const float*)d_in[1];
    const float* Kin  = (const float*)d_in[2];
    const float* Vin  = (const float*)d_in[3];
    const float* Rin  = (const float*)d_in[4];
    const float* nq   = (const float*)d_in[5];
    const float* nk   = (const float*)d_in[6];
    const float* nv   = (const float*)d_in[7];
    const float* nz   = (const float*)d_in[8];
    const int*   tptr = (const int*)d_in[9];
    const float* wq_w = (const float*)d_in[10];
    const float* wq_b = (const float*)d_in[11];
    const float* wk_w = (const float*)d_in[12];
    const float* wk_b = (const float*)d_in[13];
    const float* wv_w = (const float*)d_in[14];
    const float* wv_b = (const float*)d_in[15];
    const float* wz_w = (const float*)d_in[16];
    const float* wz_b = (const float*)d_in[17];
    const float* ln1g = (const float*)d_in[18];
    const float* ln1b = (const float*)d_in[19];
    const float* w1   = (const float*)d_in[20];
    const float* b1   = (const float*)d_in[21];
    const float* w2   = (const float*)d_in[22];
    const float* b2   = (const float*)d_in[23];
    const float* ln2g = (const float*)d_in[24];
    const float* ln2b = (const float*)d_in[25];
    const float* outw = (const float*)d_in[26];
    const float* outb = (const float*)d_in[27];

    float* out = (float*)d_out;
    const size_t R_ELEMS    = (size_t)BP_TOT * DM;        // 81920
    const size_t ATTN_ELEMS = (size_t)BP_TOT * SL;        // 163840
    const size_t KVR_ELEMS  = (size_t)BP_TOT * SL * DM;   // 41943040
    float* r_out    = out;
    float* attn_out = out + R_ELEMS;
    float* K_out    = out + R_ELEMS + ATTN_ELEMS;
    float* V_out    = K_out + KVR_ELEMS;
    float* R_out    = V_out + KVR_ELEMS;
    float* w_out    = R_out + KVR_ELEMS;

    float* knew = (float*)d_ws;
    float* vnew = knew + R_ELEMS;
    int*   i_t  = (int*)(vnew + R_ELEMS);

    fwd_kernel<<<BP_TOT, 1024, 0, stream>>>(
        x, Kin, Vin, nq, nk, nv, nz,
        wq_w, wq_b, wk_w, wk_b, wv_w, wv_b, wz_w, wz_b,
        ln1g, ln1b, w1, b1, w2, b2, ln2g, ln2b,
        tptr, r_out, attn_out, knew, vnew);

    weights_kernel<<<BATCH, 320, 0, stream>>>(
        r_out, y, outw, outb, w_out, i_t);

    resample_kernel<<<dim3(163840 / 4, 3), 256, 0, stream>>>(
        Kin, Vin, Rin, knew, vnew, r_out, i_t, tptr,
        K_out, V_out, R_out);
}

// Round 4
// 355.813 us; speedup vs baseline: 1.5874x; 1.1442x over previous
//
#include <hip/hip_runtime.h>
#include <hip/hip_bf16.h>
#include <stdint.h>

#define BATCH 32
#define NPART 10
#define BP_TOT 320
#define DM 256
#define FF 1024
#define OD 32
#define SL 512

#define SQRT_SIGMA 0.31622776601683794f

// ---------------- threefry2x32 (JAX-exact, key = (0, 42)) ----------------
__device__ __forceinline__ uint32_t rotl32(uint32_t x, uint32_t r) {
    return (x << r) | (x >> (32u - r));
}

__device__ __forceinline__ void threefry2x32(uint32_t k0, uint32_t k1,
                                             uint32_t x0, uint32_t x1,
                                             uint32_t& o0, uint32_t& o1) {
    uint32_t k2 = k0 ^ k1 ^ 0x1BD11BDAu;
    uint32_t x = x0 + k0, y = x1 + k1;
#define TFR(r) { x += y; y = rotl32(y, r); y ^= x; }
    TFR(13u) TFR(15u) TFR(26u) TFR(6u)
    x += k1; y += k2 + 1u;
    TFR(17u) TFR(29u) TFR(16u) TFR(24u)
    x += k2; y += k0 + 2u;
    TFR(13u) TFR(15u) TFR(26u) TFR(6u)
    x += k0; y += k1 + 3u;
    TFR(17u) TFR(29u) TFR(16u) TFR(24u)
    x += k1; y += k2 + 4u;
    TFR(13u) TFR(15u) TFR(26u) TFR(6u)
    x += k2; y += k0 + 5u;
#undef TFR
    o0 = x; o1 = y;
}

// JAX partitionable-mode bits: element m uses counter (0, m), bits = o0 ^ o1.
__device__ __forceinline__ float jax_gumbel_part(uint32_t m) {
    const float TINY = 1.17549435e-38f;
    uint32_t o0, o1;
    threefry2x32(0u, 42u, 0u, m, o0, o1);
    uint32_t bits = o0 ^ o1;
    uint32_t fb = (bits >> 9) | 0x3f800000u;
    float f = __uint_as_float(fb) - 1.0f;
    float u = fmaxf(TINY, f + TINY);
    return -logf(-logf(u));
}

// ---------------- K1: QKV projections, grid (320, 3) ----------------
// m==0: q -> qtmp (= attn_out row head, overwritten later by attention weights)
// m==1: k -> knew (ws)    m==2: v -> vnew (ws)
__global__ __launch_bounds__(256) void qkv_kernel(
    const float* __restrict__ x,
    const float* __restrict__ nq, const float* __restrict__ nk,
    const float* __restrict__ nv,
    const float* __restrict__ wq_w, const float* __restrict__ wq_b,
    const float* __restrict__ wk_w, const float* __restrict__ wk_b,
    const float* __restrict__ wv_w, const float* __restrict__ wv_b,
    float* __restrict__ qtmp, float* __restrict__ knew, float* __restrict__ vnew)
{
    const int bp = blockIdx.x;
    const int m  = blockIdx.y;
    const int d  = threadIdx.x;

    __shared__ float xs[DM];
    xs[d] = x[bp * DM + d];
    __syncthreads();

    const float* W; const float* bias; const float* noise; float* outp;
    if (m == 0)      { W = wq_w; bias = wq_b; noise = nq; outp = qtmp + (size_t)bp * SL; }
    else if (m == 1) { W = wk_w; bias = wk_b; noise = nk; outp = knew + (size_t)bp * DM; }
    else             { W = wv_w; bias = wv_b; noise = nv; outp = vnew + (size_t)bp * DM; }

    float a0 = 0.f, a1 = 0.f, a2 = 0.f, a3 = 0.f;
    #pragma unroll 4
    for (int i = 0; i < 64; ++i) {
        a0 = fmaf(xs[i],       W[(i      ) * DM + d], a0);
        a1 = fmaf(xs[i +  64], W[(i +  64) * DM + d], a1);
        a2 = fmaf(xs[i + 128], W[(i + 128) * DM + d], a2);
        a3 = fmaf(xs[i + 192], W[(i + 192) * DM + d], a3);
    }
    outp[d] = (a0 + a1) + (a2 + a3) + bias[d] + SQRT_SIGMA * noise[bp * DM + d];
}

// ---------------- K2: attention (logits + softmax + z), 320 x 1024 ----------------
// Reads q from qtmp(=attn_out head), k/v row t from ws; writes attn weights to
// attn_out and z to ztmp (= r_out, overwritten later by K3).
__global__ __launch_bounds__(1024) void attn_kernel(
    const float* __restrict__ Kin, const float* __restrict__ Vin,
    const float* __restrict__ knew, const float* __restrict__ vnew,
    const int* __restrict__ t_ptr,
    float* __restrict__ attn_out, float* __restrict__ ztmp)
{
    const int bp   = blockIdx.x;
    const int tid  = threadIdx.x;
    const int lane = tid & 63;
    const int wave = tid >> 6;       // 0..15
    const int t    = *t_ptr;

    __shared__ float qs[DM], ks[DM], vs[DM];
    __shared__ float att[SL];
    __shared__ float scratch[16 * 256];
    __shared__ float red[32];

    if (tid < DM) {
        qs[tid] = attn_out[(size_t)bp * SL + tid];
        ks[tid] = knew[(size_t)bp * DM + tid];
        vs[tid] = vnew[(size_t)bp * DM + tid];
    }
    __syncthreads();

    const float* Kbp = Kin + (size_t)bp * SL * DM;
    const float* Vbp = Vin + (size_t)bp * SL * DM;
    float4 q4 = *(const float4*)&qs[lane * 4];
    const int s0 = wave * 32;

    // ---- logits: 32 rows/wave, 8 loads in flight ----
    for (int j0 = 0; j0 < 32; j0 += 8) {
        float4 k4[8];
        #pragma unroll
        for (int u = 0; u < 8; ++u) {
            int s = s0 + j0 + u;
            k4[u] = (s == t) ? *(const float4*)&ks[lane * 4]
                             : *(const float4*)&Kbp[(size_t)s * DM + lane * 4];
        }
        #pragma unroll
        for (int u = 0; u < 8; ++u) {
            float acc = q4.x * k4[u].x + q4.y * k4[u].y + q4.z * k4[u].z + q4.w * k4[u].w;
            #pragma unroll
            for (int off = 32; off; off >>= 1) acc += __shfl_down(acc, off);
            if (lane == 0) att[s0 + j0 + u] = acc * 0.0625f;
        }
    }
    __syncthreads();

    // ---- softmax over 512 ----
    {
        float l = (tid < SL) ? att[tid] : -3.402823466e+38f;
        float m = l;
        #pragma unroll
        for (int off = 32; off; off >>= 1) m = fmaxf(m, __shfl_down(m, off));
        if (lane == 0) red[wave] = m;
        __syncthreads();
        float gm = red[0];
        #pragma unroll
        for (int i = 1; i < 16; ++i) gm = fmaxf(gm, red[i]);
        float e = (tid < SL) ? expf(l - gm) : 0.f;
        float ssum = e;
        #pragma unroll
        for (int off = 32; off; off >>= 1) ssum += __shfl_down(ssum, off);
        if (lane == 0) red[16 + wave] = ssum;
        __syncthreads();
        float tot = 0.f;
        #pragma unroll
        for (int i = 0; i < 16; ++i) tot += red[16 + i];
        float a = e / tot;
        if (tid < SL) {
            att[tid] = a;
            attn_out[(size_t)bp * SL + tid] = a;
        }
    }
    __syncthreads();

    // ---- z = att @ V: 32 rows/wave, 8 loads in flight ----
    {
        float4 z4 = make_float4(0.f, 0.f, 0.f, 0.f);
        for (int j0 = 0; j0 < 32; j0 += 8) {
            float4 v4[8];
            #pragma unroll
            for (int u = 0; u < 8; ++u) {
                int s = s0 + j0 + u;
                v4[u] = (s == t) ? *(const float4*)&vs[lane * 4]
                                 : *(const float4*)&Vbp[(size_t)s * DM + lane * 4];
            }
            #pragma unroll
            for (int u = 0; u < 8; ++u) {
                float a = att[s0 + j0 + u];
                z4.x = fmaf(a, v4[u].x, z4.x);
                z4.y = fmaf(a, v4[u].y, z4.y);
                z4.z = fmaf(a, v4[u].z, z4.z);
                z4.w = fmaf(a, v4[u].w, z4.w);
            }
        }
        *(float4*)&scratch[wave * 256 + lane * 4] = z4;
    }
    __syncthreads();
    if (tid < DM) {
        float z = 0.f;
        #pragma unroll
        for (int w = 0; w < 16; ++w) z += scratch[w * 256 + tid];
        ztmp[(size_t)bp * DM + tid] = z;
    }
}

// ---------------- K3: zproj + LN1 + FFN + LN2, 320 x 1024 ----------------
__global__ __launch_bounds__(1024) void post_kernel(
    const float* __restrict__ x, const float* __restrict__ nz,
    const float* __restrict__ wz_w, const float* __restrict__ wz_b,
    const float* __restrict__ ln1_g, const float* __restrict__ ln1_b,
    const float* __restrict__ w1, const float* __restrict__ b1,
    const float* __restrict__ w2, const float* __restrict__ b2,
    const float* __restrict__ ln2_g, const float* __restrict__ ln2_b,
    float* __restrict__ r_out)   // holds z on entry
{
    const int bp   = blockIdx.x;
    const int tid  = threadIdx.x;
    const int lane = tid & 63;
    const int wave = tid >> 6;
    const int grp  = tid >> 8;      // 0..3
    const int qtid = tid & 255;

    __shared__ float buf[DM];       // z, then ln1-out
    __shared__ float xs[DM];
    __shared__ float hid[FF];
    __shared__ float scratch[1024];
    __shared__ float red[32];

    if (tid < DM) {
        buf[tid] = r_out[(size_t)bp * DM + tid];
        xs[tid]  = x[bp * DM + tid];
    }
    __syncthreads();

    // ---- z projection, i-split 4 ways, 2 accs ----
    {
        const int i0 = grp * 64;
        float a0 = 0.f, a1 = 0.f;
        #pragma unroll 4
        for (int ii = 0; ii < 32; ++ii) {
            a0 = fmaf(buf[i0 + ii],      wz_w[(i0 + ii)      * DM + qtid], a0);
            a1 = fmaf(buf[i0 + ii + 32], wz_w[(i0 + ii + 32) * DM + qtid], a1);
        }
        scratch[grp * 256 + qtid] = a0 + a1;
    }
    __syncthreads();
    float h = 0.f;
    if (tid < DM) {
        float az = (scratch[tid] + scratch[256 + tid]) + (scratch[512 + tid] + scratch[768 + tid]);
        h = az + wz_b[tid] + SQRT_SIGMA * nz[bp * DM + tid] + xs[tid];
    }

    // ---- layernorm 1 (values in waves 0..3) ----
    float s1 = h;
    #pragma unroll
    for (int off = 32; off; off >>= 1) s1 += __shfl_down(s1, off);
    if (lane == 0) red[wave] = s1;
    __syncthreads();
    float mu = (red[0] + red[1] + red[2] + red[3]) * (1.0f / DM);
    float dv = (tid < DM) ? (h - mu) : 0.f;
    float s2 = dv * dv;
    #pragma unroll
    for (int off = 32; off; off >>= 1) s2 += __shfl_down(s2, off);
    if (lane == 0) red[16 + wave] = s2;
    __syncthreads();
    float var = (red[16] + red[17] + red[18] + red[19]) * (1.0f / DM);
    float o = 0.f;
    __syncthreads();
    if (tid < DM) {
        o = dv * rsqrtf(var + 1e-6f) * ln1_g[tid] + ln1_b[tid];
        buf[tid] = o;
    }
    __syncthreads();

    // ---- FFN1 (256 -> 1024), one output/thread, 4 accs ----
    {
        float h0 = 0.f, h1 = 0.f, h2 = 0.f, h3 = 0.f;
        #pragma unroll 4
        for (int i = 0; i < 64; ++i) {
            h0 = fmaf(buf[i],       w1[(i      ) * FF + tid], h0);
            h1 = fmaf(buf[i +  64], w1[(i +  64) * FF + tid], h1);
            h2 = fmaf(buf[i + 128], w1[(i + 128) * FF + tid], h2);
            h3 = fmaf(buf[i + 192], w1[(i + 192) * FF + tid], h3);
        }
        hid[tid] = fmaxf((h0 + h1) + (h2 + h3) + b1[tid], 0.f);
    }
    __syncthreads();

    // ---- FFN2 (1024 -> 256), i-split 4 ways, 4 accs ----
    {
        const int i0 = grp * 256;
        float a0 = 0.f, a1 = 0.f, a2 = 0.f, a3 = 0.f;
        #pragma unroll 4
        for (int ii = 0; ii < 64; ++ii) {
            a0 = fmaf(hid[i0 + ii],       w2[(i0 + ii      ) * DM + qtid], a0);
            a1 = fmaf(hid[i0 + ii +  64], w2[(i0 + ii +  64) * DM + qtid], a1);
            a2 = fmaf(hid[i0 + ii + 128], w2[(i0 + ii + 128) * DM + qtid], a2);
            a3 = fmaf(hid[i0 + ii + 192], w2[(i0 + ii + 192) * DM + qtid], a3);
        }
        scratch[grp * 256 + qtid] = (a0 + a1) + (a2 + a3);
    }
    __syncthreads();
    float rr = 0.f;
    if (tid < DM) {
        rr = (scratch[tid] + scratch[256 + tid]) + (scratch[512 + tid] + scratch[768 + tid])
           + b2[tid] + o;
    }

    // ---- layernorm 2 ----
    float t1 = rr;
    #pragma unroll
    for (int off = 32; off; off >>= 1) t1 += __shfl_down(t1, off);
    if (lane == 0) red[wave] = t1;
    __syncthreads();
    float mu2 = (red[0] + red[1] + red[2] + red[3]) * (1.0f / DM);
    float dv2 = (tid < DM) ? (rr - mu2) : 0.f;
    float t2 = dv2 * dv2;
    #pragma unroll
    for (int off = 32; off; off >>= 1) t2 += __shfl_down(t2, off);
    if (lane == 0) red[16 + wave] = t2;
    __syncthreads();
    float var2 = (red[16] + red[17] + red[18] + red[19]) * (1.0f / DM);
    if (tid < DM) {
        float rf = dv2 * rsqrtf(var2 + 1e-6f) * ln2_g[tid] + ln2_b[tid];
        r_out[(size_t)bp * DM + tid] = rf;
    }
}

// ---------------- K4: particle weights + resample indices ----------------
__global__ __launch_bounds__(320) void weights_kernel(
    const float* __restrict__ r, const float* __restrict__ y,
    const float* __restrict__ out_w, const float* __restrict__ out_b,
    float* __restrict__ w_out, int* __restrict__ i_t)
{
    const int b   = blockIdx.x;    // 0..31
    const int tid = threadIdx.x;   // 0..319
    const int p   = tid >> 5;      // 0..9
    const int j   = tid & 31;      // 0..31

    __shared__ float sred[NPART];
    __shared__ float es[NPART];
    __shared__ float pe[NPART];
    __shared__ float wsm[NPART];

    const float* rrow = r + (size_t)(b * NPART + p) * DM;
    float acc = 0.f;
    #pragma unroll 4
    for (int i = 0; i < DM; ++i) acc = fmaf(rrow[i], out_w[i * OD + j], acc);
    float pred = acc + out_b[j];
    float muv  = y[(size_t)(b * NPART + p) * OD + j] - pred;
    float s    = muv * muv;
    #pragma unroll
    for (int off = 16; off; off >>= 1) s += __shfl_down(s, off, 32);
    if (j == 0) sred[p] = s;   // log_w = -s
    __syncthreads();

    if (tid < NPART) es[tid] = expf(-sred[tid]);
    __syncthreads();
    if (tid < NPART) {
        float mx = es[0];
        #pragma unroll
        for (int i = 1; i < NPART; ++i) mx = fmaxf(mx, es[i]);
        pe[tid] = expf(es[tid] - mx);
    }
    __syncthreads();
    if (tid < NPART) {
        float sum = 0.f;
        #pragma unroll
        for (int i = 0; i < NPART; ++i) sum += pe[i];
        float wv = pe[tid] / sum;
        w_out[b * NPART + tid] = wv;
        wsm[tid] = wv;
    }
    __syncthreads();

    if (tid < NPART) {
        int pp = tid;
        int best = 0;
        float bests = -3.402823466e+38f;
        #pragma unroll
        for (int jj = 0; jj < NPART; ++jj) {
            uint32_t m = (uint32_t)(b * 100 + pp * 10 + jj);
            float score = jax_gumbel_part(m) + wsm[jj];
            if (score > bests) { bests = score; best = jj; }
        }
        i_t[b * NPART + pp] = best;
    }
}

// ---------------- K5: resample gather-copy of K, V, R ----------------
__global__ __launch_bounds__(256) void resample_kernel(
    const float* __restrict__ Kin, const float* __restrict__ Vin,
    const float* __restrict__ Rin,
    const float* __restrict__ knew, const float* __restrict__ vnew,
    const float* __restrict__ rnew,
    const int* __restrict__ i_t, const int* __restrict__ t_ptr,
    float* __restrict__ Kout, float* __restrict__ Vout, float* __restrict__ Rout)
{
    const int t      = *t_ptr;
    const int tensor = blockIdx.y;          // 0=K 1=V 2=R
    const int tid    = threadIdx.x;
    size_t idx  = (size_t)blockIdx.x * 256 + tid;
    int lane4 = (int)(idx & 63);            // float4 slot within row
    int row   = (int)(idx >> 6);            // 0..163839
    int bpi   = row >> 9;                   // 0..319
    int s     = row & 511;
    int b     = bpi / NPART;
    int p     = bpi - b * NPART;
    int srcp  = (s <= t) ? i_t[bpi] : p;
    int src_bpi = b * NPART + srcp;

    const float* src;
    if (s == t) {
        const float* nb = (tensor == 0) ? knew : (tensor == 1) ? vnew : rnew;
        src = nb + (size_t)src_bpi * DM;
    } else {
        const float* base = (tensor == 0) ? Kin : (tensor == 1) ? Vin : Rin;
        src = base + ((size_t)src_bpi * SL + s) * DM;
    }
    float* outb = (tensor == 0) ? Kout : (tensor == 1) ? Vout : Rout;
    float4 v4 = *(const float4*)(src + (size_t)lane4 * 4);
    *(float4*)(outb + (size_t)row * DM + (size_t)lane4 * 4) = v4;
}

// ---------------- launch ----------------
extern "C" void kernel_launch(void* const* d_in, const int* in_sizes, int n_in,
                              void* d_out, int out_size, void* d_ws, size_t ws_size,
                              hipStream_t stream) {
    const float* x    = (const float*)d_in[0];
    const float* y    = (const float*)d_in[1];
    const float* Kin  = (const float*)d_in[2];
    const float* Vin  = (const float*)d_in[3];
    const float* Rin  = (const float*)d_in[4];
    const float* nq   = (const float*)d_in[5];
    const float* nk   = (const float*)d_in[6];
    const float* nv   = (const float*)d_in[7];
    const float* nz   = (const float*)d_in[8];
    const int*   tptr = (const int*)d_in[9];
    const float* wq_w = (const float*)d_in[10];
    const float* wq_b = (const float*)d_in[11];
    const float* wk_w = (const float*)d_in[12];
    const float* wk_b = (const float*)d_in[13];
    const float* wv_w = (const float*)d_in[14];
    const float* wv_b = (const float*)d_in[15];
    const float* wz_w = (const float*)d_in[16];
    const float* wz_b = (const float*)d_in[17];
    const float* ln1g = (const float*)d_in[18];
    const float* ln1b = (const float*)d_in[19];
    const float* w1   = (const float*)d_in[20];
    const float* b1   = (const float*)d_in[21];
    const float* w2   = (const float*)d_in[22];
    const float* b2   = (const float*)d_in[23];
    const float* ln2g = (const float*)d_in[24];
    const float* ln2b = (const float*)d_in[25];
    const float* outw = (const float*)d_in[26];
    const float* outb = (const float*)d_in[27];

    float* out = (float*)d_out;
    const size_t R_ELEMS    = (size_t)BP_TOT * DM;        // 81920
    const size_t ATTN_ELEMS = (size_t)BP_TOT * SL;        // 163840
    const size_t KVR_ELEMS  = (size_t)BP_TOT * SL * DM;   // 41943040
    float* r_out    = out;
    float* attn_out = out + R_ELEMS;
    float* K_out    = out + R_ELEMS + ATTN_ELEMS;
    float* V_out    = K_out + KVR_ELEMS;
    float* R_out    = V_out + KVR_ELEMS;
    float* w_out    = R_out + KVR_ELEMS;

    float* knew = (float*)d_ws;
    float* vnew = knew + R_ELEMS;
    int*   i_t  = (int*)(vnew + R_ELEMS);

    // K1: q -> attn_out[:, :256] (scratch), k/v -> ws
    qkv_kernel<<<dim3(BP_TOT, 3), 256, 0, stream>>>(
        x, nq, nk, nv, wq_w, wq_b, wk_w, wk_b, wv_w, wv_b,
        attn_out, knew, vnew);

    // K2: attention; z -> r_out (scratch), attn weights -> attn_out
    attn_kernel<<<BP_TOT, 1024, 0, stream>>>(
        Kin, Vin, knew, vnew, tptr, attn_out, r_out);

    // K3: zproj + LN1 + FFN + LN2; r_out finalized
    post_kernel<<<BP_TOT, 1024, 0, stream>>>(
        x, nz, wz_w, wz_b, ln1g, ln1b, w1, b1, w2, b2, ln2g, ln2b,
        r_out);

    weights_kernel<<<BATCH, 320, 0, stream>>>(
        r_out, y, outw, outb, w_out, i_t);

    resample_kernel<<<dim3(163840 / 4, 3), 256, 0, stream>>>(
        Kin, Vin, Rin, knew, vnew, r_out, i_t, tptr,
        K_out, V_out, R_out);
}

// Round 5
// 342.254 us; speedup vs baseline: 1.6503x; 1.0396x over previous
//
#include <hip/hip_runtime.h>
#include <hip/hip_bf16.h>
#include <stdint.h>

#define BATCH 32
#define NPART 10
#define BP_TOT 320
#define DM 256
#define FF 1024
#define OD 32
#define SL 512

#define SQRT_SIGMA 0.31622776601683794f

// ---------------- threefry2x32 (JAX-exact, key = (0, 42)) ----------------
__device__ __forceinline__ uint32_t rotl32(uint32_t x, uint32_t r) {
    return (x << r) | (x >> (32u - r));
}

__device__ __forceinline__ void threefry2x32(uint32_t k0, uint32_t k1,
                                             uint32_t x0, uint32_t x1,
                                             uint32_t& o0, uint32_t& o1) {
    uint32_t k2 = k0 ^ k1 ^ 0x1BD11BDAu;
    uint32_t x = x0 + k0, y = x1 + k1;
#define TFR(r) { x += y; y = rotl32(y, r); y ^= x; }
    TFR(13u) TFR(15u) TFR(26u) TFR(6u)
    x += k1; y += k2 + 1u;
    TFR(17u) TFR(29u) TFR(16u) TFR(24u)
    x += k2; y += k0 + 2u;
    TFR(13u) TFR(15u) TFR(26u) TFR(6u)
    x += k0; y += k1 + 3u;
    TFR(17u) TFR(29u) TFR(16u) TFR(24u)
    x += k1; y += k2 + 4u;
    TFR(13u) TFR(15u) TFR(26u) TFR(6u)
    x += k2; y += k0 + 5u;
#undef TFR
    o0 = x; o1 = y;
}

// JAX partitionable-mode bits: element m uses counter (0, m), bits = o0 ^ o1.
__device__ __forceinline__ float jax_gumbel_part(uint32_t m) {
    const float TINY = 1.17549435e-38f;
    uint32_t o0, o1;
    threefry2x32(0u, 42u, 0u, m, o0, o1);
    uint32_t bits = o0 ^ o1;
    uint32_t fb = (bits >> 9) | 0x3f800000u;
    float f = __uint_as_float(fb) - 1.0f;
    float u = fmaxf(TINY, f + TINY);
    return -logf(-logf(u));
}

// ---------------- K1: QKV projections, grid (320, 3) ----------------
__global__ __launch_bounds__(256) void qkv_kernel(
    const float* __restrict__ x,
    const float* __restrict__ nq, const float* __restrict__ nk,
    const float* __restrict__ nv,
    const float* __restrict__ wq_w, const float* __restrict__ wq_b,
    const float* __restrict__ wk_w, const float* __restrict__ wk_b,
    const float* __restrict__ wv_w, const float* __restrict__ wv_b,
    float* __restrict__ qtmp, float* __restrict__ knew, float* __restrict__ vnew)
{
    const int bp = blockIdx.x;
    const int m  = blockIdx.y;
    const int d  = threadIdx.x;

    __shared__ float xs[DM];
    xs[d] = x[bp * DM + d];
    __syncthreads();

    const float* W; const float* bias; const float* noise; float* outp;
    if (m == 0)      { W = wq_w; bias = wq_b; noise = nq; outp = qtmp + (size_t)bp * SL; }
    else if (m == 1) { W = wk_w; bias = wk_b; noise = nk; outp = knew + (size_t)bp * DM; }
    else             { W = wv_w; bias = wv_b; noise = nv; outp = vnew + (size_t)bp * DM; }

    float a0 = 0.f, a1 = 0.f, a2 = 0.f, a3 = 0.f;
    #pragma unroll 4
    for (int i = 0; i < 64; ++i) {
        a0 = fmaf(xs[i],       W[(i      ) * DM + d], a0);
        a1 = fmaf(xs[i +  64], W[(i +  64) * DM + d], a1);
        a2 = fmaf(xs[i + 128], W[(i + 128) * DM + d], a2);
        a3 = fmaf(xs[i + 192], W[(i + 192) * DM + d], a3);
    }
    outp[d] = (a0 + a1) + (a2 + a3) + bias[d] + SQRT_SIGMA * noise[bp * DM + d];
}

// ---------------- K2a: logits, grid (320, 4) x 256 ----------------
// Each block: 128 rows of K. Writes raw logits to scratch (K_out head region).
__global__ __launch_bounds__(256) void logits_kernel(
    const float* __restrict__ Kin, const float* __restrict__ knew,
    const float* __restrict__ qtmp, const int* __restrict__ t_ptr,
    float* __restrict__ logits)
{
    const int bp   = blockIdx.x;
    const int sc   = blockIdx.y;        // 0..3
    const int tid  = threadIdx.x;
    const int lane = tid & 63;
    const int wave = tid >> 6;          // 0..3
    const int t    = *t_ptr;

    __shared__ float qs[DM], ks[DM];
    if (tid < DM) {
        qs[tid] = qtmp[(size_t)bp * SL + tid];
        ks[tid] = knew[(size_t)bp * DM + tid];
    }
    __syncthreads();

    const float* Kbp = Kin + (size_t)bp * SL * DM;
    float4 q4 = *(const float4*)&qs[lane * 4];
    const int s0 = sc * 128 + wave * 32;

    for (int j0 = 0; j0 < 32; j0 += 8) {
        float4 k4[8];
        #pragma unroll
        for (int u = 0; u < 8; ++u) {
            int s = s0 + j0 + u;
            k4[u] = (s == t) ? *(const float4*)&ks[lane * 4]
                             : *(const float4*)&Kbp[(size_t)s * DM + lane * 4];
        }
        #pragma unroll
        for (int u = 0; u < 8; ++u) {
            float acc = q4.x * k4[u].x + q4.y * k4[u].y + q4.z * k4[u].z + q4.w * k4[u].w;
            #pragma unroll
            for (int off = 32; off; off >>= 1) acc += __shfl_down(acc, off);
            if (lane == 0) logits[(size_t)bp * SL + s0 + j0 + u] = acc * 0.0625f;
        }
    }
}

// ---------------- K2b: softmax + z-partial, grid (320, 4) x 256 ----------------
// Every block recomputes the full softmax from the 512 logits (L2-hot);
// block sc==0 writes attn weights; each block accumulates z over its 128 rows
// and writes a 256-float partial to zpart (V_out head region).
__global__ __launch_bounds__(256) void attnz_kernel(
    const float* __restrict__ Vin, const float* __restrict__ vnew,
    const float* __restrict__ logits, const int* __restrict__ t_ptr,
    float* __restrict__ attn_out, float* __restrict__ zpart)
{
    const int bp   = blockIdx.x;
    const int sc   = blockIdx.y;        // 0..3
    const int tid  = threadIdx.x;
    const int lane = tid & 63;
    const int wave = tid >> 6;          // 0..3
    const int t    = *t_ptr;

    __shared__ float att[SL];
    __shared__ float vs[DM];
    __shared__ float scratch[4 * 256];
    __shared__ float red[8];

    if (tid < DM) vs[tid] = vnew[(size_t)bp * DM + tid];

    float l0 = logits[(size_t)bp * SL + tid];
    float l1 = logits[(size_t)bp * SL + tid + 256];
    float m = fmaxf(l0, l1);
    #pragma unroll
    for (int off = 32; off; off >>= 1) m = fmaxf(m, __shfl_down(m, off));
    if (lane == 0) red[wave] = m;
    __syncthreads();
    float gm = fmaxf(fmaxf(red[0], red[1]), fmaxf(red[2], red[3]));
    float e0 = expf(l0 - gm), e1 = expf(l1 - gm);
    float ssum = e0 + e1;
    #pragma unroll
    for (int off = 32; off; off >>= 1) ssum += __shfl_down(ssum, off);
    if (lane == 0) red[4 + wave] = ssum;
    __syncthreads();
    float inv = 1.0f / (red[4] + red[5] + red[6] + red[7]);
    float a0 = e0 * inv, a1 = e1 * inv;
    att[tid] = a0; att[tid + 256] = a1;
    if (sc == 0) {
        attn_out[(size_t)bp * SL + tid]       = a0;
        attn_out[(size_t)bp * SL + tid + 256] = a1;
    }
    __syncthreads();

    // z-partial over rows [sc*128, sc*128+128)
    const float* Vbp = Vin + (size_t)bp * SL * DM;
    const int s0 = sc * 128 + wave * 32;
    float4 z4 = make_float4(0.f, 0.f, 0.f, 0.f);
    for (int j0 = 0; j0 < 32; j0 += 8) {
        float4 v4[8];
        #pragma unroll
        for (int u = 0; u < 8; ++u) {
            int s = s0 + j0 + u;
            v4[u] = (s == t) ? *(const float4*)&vs[lane * 4]
                             : *(const float4*)&Vbp[(size_t)s * DM + lane * 4];
        }
        #pragma unroll
        for (int u = 0; u < 8; ++u) {
            float a = att[s0 + j0 + u];
            z4.x = fmaf(a, v4[u].x, z4.x);
            z4.y = fmaf(a, v4[u].y, z4.y);
            z4.z = fmaf(a, v4[u].z, z4.z);
            z4.w = fmaf(a, v4[u].w, z4.w);
        }
    }
    *(float4*)&scratch[wave * 256 + lane * 4] = z4;
    __syncthreads();
    if (tid < DM) {
        float zp = (scratch[tid] + scratch[256 + tid]) + (scratch[512 + tid] + scratch[768 + tid]);
        zpart[(size_t)bp * 1024 + sc * 256 + tid] = zp;
    }
}

// ---------------- K3: zsum + zproj + LN1 + FFN + LN2, 320 x 1024 ----------------
__global__ __launch_bounds__(1024) void post_kernel(
    const float* __restrict__ x, const float* __restrict__ nz,
    const float* __restrict__ zpart,
    const float* __restrict__ wz_w, const float* __restrict__ wz_b,
    const float* __restrict__ ln1_g, const float* __restrict__ ln1_b,
    const float* __restrict__ w1, const float* __restrict__ b1,
    const float* __restrict__ w2, const float* __restrict__ b2,
    const float* __restrict__ ln2_g, const float* __restrict__ ln2_b,
    float* __restrict__ r_out)
{
    const int bp   = blockIdx.x;
    const int tid  = threadIdx.x;
    const int lane = tid & 63;
    const int wave = tid >> 6;
    const int grp  = tid >> 8;      // 0..3
    const int qtid = tid & 255;

    __shared__ float buf[DM];       // z, then ln1-out
    __shared__ float xs[DM];
    __shared__ float hid[FF];
    __shared__ float scratch[1024];
    __shared__ float red[32];

    if (tid < DM) {
        const float* zp = zpart + (size_t)bp * 1024;
        buf[tid] = (zp[tid] + zp[256 + tid]) + (zp[512 + tid] + zp[768 + tid]);
        xs[tid]  = x[bp * DM + tid];
    }
    __syncthreads();

    // ---- z projection, i-split 4 ways ----
    {
        const int i0 = grp * 64;
        float a0 = 0.f, a1 = 0.f;
        #pragma unroll 4
        for (int ii = 0; ii < 32; ++ii) {
            a0 = fmaf(buf[i0 + ii],      wz_w[(i0 + ii)      * DM + qtid], a0);
            a1 = fmaf(buf[i0 + ii + 32], wz_w[(i0 + ii + 32) * DM + qtid], a1);
        }
        scratch[grp * 256 + qtid] = a0 + a1;
    }
    __syncthreads();
    float h = 0.f;
    if (tid < DM) {
        float az = (scratch[tid] + scratch[256 + tid]) + (scratch[512 + tid] + scratch[768 + tid]);
        h = az + wz_b[tid] + SQRT_SIGMA * nz[bp * DM + tid] + xs[tid];
    }

    // ---- layernorm 1 ----
    float s1 = h;
    #pragma unroll
    for (int off = 32; off; off >>= 1) s1 += __shfl_down(s1, off);
    if (lane == 0) red[wave] = s1;
    __syncthreads();
    float mu = (red[0] + red[1] + red[2] + red[3]) * (1.0f / DM);
    float dv = (tid < DM) ? (h - mu) : 0.f;
    float s2 = dv * dv;
    #pragma unroll
    for (int off = 32; off; off >>= 1) s2 += __shfl_down(s2, off);
    if (lane == 0) red[16 + wave] = s2;
    __syncthreads();
    float var = (red[16] + red[17] + red[18] + red[19]) * (1.0f / DM);
    float o = 0.f;
    __syncthreads();
    if (tid < DM) {
        o = dv * rsqrtf(var + 1e-6f) * ln1_g[tid] + ln1_b[tid];
        buf[tid] = o;
    }
    __syncthreads();

    // ---- FFN1 (256 -> 1024) ----
    {
        float h0 = 0.f, h1 = 0.f, h2 = 0.f, h3 = 0.f;
        #pragma unroll 4
        for (int i = 0; i < 64; ++i) {
            h0 = fmaf(buf[i],       w1[(i      ) * FF + tid], h0);
            h1 = fmaf(buf[i +  64], w1[(i +  64) * FF + tid], h1);
            h2 = fmaf(buf[i + 128], w1[(i + 128) * FF + tid], h2);
            h3 = fmaf(buf[i + 192], w1[(i + 192) * FF + tid], h3);
        }
        hid[tid] = fmaxf((h0 + h1) + (h2 + h3) + b1[tid], 0.f);
    }
    __syncthreads();

    // ---- FFN2 (1024 -> 256), i-split 4 ways ----
    {
        const int i0 = grp * 256;
        float a0 = 0.f, a1 = 0.f, a2 = 0.f, a3 = 0.f;
        #pragma unroll 4
        for (int ii = 0; ii < 64; ++ii) {
            a0 = fmaf(hid[i0 + ii],       w2[(i0 + ii      ) * DM + qtid], a0);
            a1 = fmaf(hid[i0 + ii +  64], w2[(i0 + ii +  64) * DM + qtid], a1);
            a2 = fmaf(hid[i0 + ii + 128], w2[(i0 + ii + 128) * DM + qtid], a2);
            a3 = fmaf(hid[i0 + ii + 192], w2[(i0 + ii + 192) * DM + qtid], a3);
        }
        scratch[grp * 256 + qtid] = (a0 + a1) + (a2 + a3);
    }
    __syncthreads();
    float rr = 0.f;
    if (tid < DM) {
        rr = (scratch[tid] + scratch[256 + tid]) + (scratch[512 + tid] + scratch[768 + tid])
           + b2[tid] + o;
    }

    // ---- layernorm 2 ----
    float t1 = rr;
    #pragma unroll
    for (int off = 32; off; off >>= 1) t1 += __shfl_down(t1, off);
    if (lane == 0) red[wave] = t1;
    __syncthreads();
    float mu2 = (red[0] + red[1] + red[2] + red[3]) * (1.0f / DM);
    float dv2 = (tid < DM) ? (rr - mu2) : 0.f;
    float t2 = dv2 * dv2;
    #pragma unroll
    for (int off = 32; off; off >>= 1) t2 += __shfl_down(t2, off);
    if (lane == 0) red[16 + wave] = t2;
    __syncthreads();
    float var2 = (red[16] + red[17] + red[18] + red[19]) * (1.0f / DM);
    if (tid < DM) {
        float rf = dv2 * rsqrtf(var2 + 1e-6f) * ln2_g[tid] + ln2_b[tid];
        r_out[(size_t)bp * DM + tid] = rf;
    }
}

// ---------------- K4: particle weights + resample indices ----------------
__global__ __launch_bounds__(320) void weights_kernel(
    const float* __restrict__ r, const float* __restrict__ y,
    const float* __restrict__ out_w, const float* __restrict__ out_b,
    float* __restrict__ w_out, int* __restrict__ i_t)
{
    const int b   = blockIdx.x;    // 0..31
    const int tid = threadIdx.x;   // 0..319
    const int p   = tid >> 5;      // 0..9
    const int j   = tid & 31;      // 0..31

    __shared__ float sred[NPART];
    __shared__ float es[NPART];
    __shared__ float pe[NPART];
    __shared__ float wsm[NPART];

    const float* rrow = r + (size_t)(b * NPART + p) * DM;
    float acc = 0.f;
    #pragma unroll 4
    for (int i = 0; i < DM; ++i) acc = fmaf(rrow[i], out_w[i * OD + j], acc);
    float pred = acc + out_b[j];
    float muv  = y[(size_t)(b * NPART + p) * OD + j] - pred;
    float s    = muv * muv;
    #pragma unroll
    for (int off = 16; off; off >>= 1) s += __shfl_down(s, off, 32);
    if (j == 0) sred[p] = s;   // log_w = -s
    __syncthreads();

    if (tid < NPART) es[tid] = expf(-sred[tid]);
    __syncthreads();
    if (tid < NPART) {
        float mx = es[0];
        #pragma unroll
        for (int i = 1; i < NPART; ++i) mx = fmaxf(mx, es[i]);
        pe[tid] = expf(es[tid] - mx);
    }
    __syncthreads();
    if (tid < NPART) {
        float sum = 0.f;
        #pragma unroll
        for (int i = 0; i < NPART; ++i) sum += pe[i];
        float wv = pe[tid] / sum;
        w_out[b * NPART + tid] = wv;
        wsm[tid] = wv;
    }
    __syncthreads();

    if (tid < NPART) {
        int pp = tid;
        int best = 0;
        float bests = -3.402823466e+38f;
        #pragma unroll
        for (int jj = 0; jj < NPART; ++jj) {
            uint32_t m = (uint32_t)(b * 100 + pp * 10 + jj);
            float score = jax_gumbel_part(m) + wsm[jj];
            if (score > bests) { bests = score; best = jj; }
        }
        i_t[b * NPART + pp] = best;
    }
}

// ---------------- K5: resample gather-copy of K, V, R ----------------
__global__ __launch_bounds__(256) void resample_kernel(
    const float* __restrict__ Kin, const float* __restrict__ Vin,
    const float* __restrict__ Rin,
    const float* __restrict__ knew, const float* __restrict__ vnew,
    const float* __restrict__ rnew,
    const int* __restrict__ i_t, const int* __restrict__ t_ptr,
    float* __restrict__ Kout, float* __restrict__ Vout, float* __restrict__ Rout)
{
    const int t      = *t_ptr;
    const int tensor = blockIdx.y;          // 0=K 1=V 2=R
    const int tid    = threadIdx.x;
    size_t idx  = (size_t)blockIdx.x * 256 + tid;
    int lane4 = (int)(idx & 63);            // float4 slot within row
    int row   = (int)(idx >> 6);            // 0..163839
    int bpi   = row >> 9;                   // 0..319
    int s     = row & 511;
    int b     = bpi / NPART;
    int p     = bpi - b * NPART;
    int srcp  = (s <= t) ? i_t[bpi] : p;
    int src_bpi = b * NPART + srcp;

    const float* src;
    if (s == t) {
        const float* nb = (tensor == 0) ? knew : (tensor == 1) ? vnew : rnew;
        src = nb + (size_t)src_bpi * DM;
    } else {
        const float* base = (tensor == 0) ? Kin : (tensor == 1) ? Vin : Rin;
        src = base + ((size_t)src_bpi * SL + s) * DM;
    }
    float* outb = (tensor == 0) ? Kout : (tensor == 1) ? Vout : Rout;
    float4 v4 = *(const float4*)(src + (size_t)lane4 * 4);
    *(float4*)(outb + (size_t)row * DM + (size_t)lane4 * 4) = v4;
}

// ---------------- launch ----------------
extern "C" void kernel_launch(void* const* d_in, const int* in_sizes, int n_in,
                              void* d_out, int out_size, void* d_ws, size_t ws_size,
                              hipStream_t stream) {
    const float* x    = (const float*)d_in[0];
    const float* y    = (const float*)d_in[1];
    const float* Kin  = (const float*)d_in[2];
    const float* Vin  = (const float*)d_in[3];
    const float* Rin  = (const float*)d_in[4];
    const float* nq   = (const float*)d_in[5];
    const float* nk   = (const float*)d_in[6];
    const float* nv   = (const float*)d_in[7];
    const float* nz   = (const float*)d_in[8];
    const int*   tptr = (const int*)d_in[9];
    const float* wq_w = (const float*)d_in[10];
    const float* wq_b = (const float*)d_in[11];
    const float* wk_w = (const float*)d_in[12];
    const float* wk_b = (const float*)d_in[13];
    const float* wv_w = (const float*)d_in[14];
    const float* wv_b = (const float*)d_in[15];
    const float* wz_w = (const float*)d_in[16];
    const float* wz_b = (const float*)d_in[17];
    const float* ln1g = (const float*)d_in[18];
    const float* ln1b = (const float*)d_in[19];
    const float* w1   = (const float*)d_in[20];
    const float* b1   = (const float*)d_in[21];
    const float* w2   = (const float*)d_in[22];
    const float* b2   = (const float*)d_in[23];
    const float* ln2g = (const float*)d_in[24];
    const float* ln2b = (const float*)d_in[25];
    const float* outw = (const float*)d_in[26];
    const float* outb = (const float*)d_in[27];

    float* out = (float*)d_out;
    const size_t R_ELEMS    = (size_t)BP_TOT * DM;        // 81920
    const size_t ATTN_ELEMS = (size_t)BP_TOT * SL;        // 163840
    const size_t KVR_ELEMS  = (size_t)BP_TOT * SL * DM;   // 41943040
    float* r_out    = out;
    float* attn_out = out + R_ELEMS;
    float* K_out    = out + R_ELEMS + ATTN_ELEMS;
    float* V_out    = K_out + KVR_ELEMS;
    float* R_out    = V_out + KVR_ELEMS;
    float* w_out    = R_out + KVR_ELEMS;

    float* knew = (float*)d_ws;
    float* vnew = knew + R_ELEMS;
    int*   i_t  = (int*)(vnew + R_ELEMS);

    // dead-until-resample scratch inside d_out:
    float* logits = K_out;     // 320*512 floats, overwritten by K5
    float* zpart  = V_out;     // 320*1024 floats, overwritten by K5

    // K1: q -> attn_out[:, :256] (scratch), k/v -> ws
    qkv_kernel<<<dim3(BP_TOT, 3), 256, 0, stream>>>(
        x, nq, nk, nv, wq_w, wq_b, wk_w, wk_b, wv_w, wv_b,
        attn_out, knew, vnew);

    // K2a: raw logits -> K_out scratch
    logits_kernel<<<dim3(BP_TOT, 4), 256, 0, stream>>>(
        Kin, knew, attn_out, tptr, logits);

    // K2b: softmax (attn_out) + z partials -> V_out scratch
    attnz_kernel<<<dim3(BP_TOT, 4), 256, 0, stream>>>(
        Vin, vnew, logits, tptr, attn_out, zpart);

    // K3: zsum + zproj + LN1 + FFN + LN2 -> r_out
    post_kernel<<<BP_TOT, 1024, 0, stream>>>(
        x, nz, zpart, wz_w, wz_b, ln1g, ln1b, w1, b1, w2, b2, ln2g, ln2b,
        r_out);

    weights_kernel<<<BATCH, 320, 0, stream>>>(
        r_out, y, outw, outb, w_out, i_t);

    resample_kernel<<<dim3(163840 / 4, 3), 256, 0, stream>>>(
        Kin, Vin, Rin, knew, vnew, r_out, i_t, tptr,
        K_out, V_out, R_out);
}

// Round 6
// 337.784 us; speedup vs baseline: 1.6722x; 1.0132x over previous
//
#include <hip/hip_runtime.h>
#include <hip/hip_bf16.h>
#include <stdint.h>

#define BATCH 32
#define NPART 10
#define BP_TOT 320
#define DM 256
#define FF 1024
#define OD 32
#define SL 512

#define SQRT_SIGMA 0.31622776601683794f

// ---------------- threefry2x32 (JAX-exact, key = (0, 42)) ----------------
__device__ __forceinline__ uint32_t rotl32(uint32_t x, uint32_t r) {
    return (x << r) | (x >> (32u - r));
}

__device__ __forceinline__ void threefry2x32(uint32_t k0, uint32_t k1,
                                             uint32_t x0, uint32_t x1,
                                             uint32_t& o0, uint32_t& o1) {
    uint32_t k2 = k0 ^ k1 ^ 0x1BD11BDAu;
    uint32_t x = x0 + k0, y = x1 + k1;
#define TFR(r) { x += y; y = rotl32(y, r); y ^= x; }
    TFR(13u) TFR(15u) TFR(26u) TFR(6u)
    x += k1; y += k2 + 1u;
    TFR(17u) TFR(29u) TFR(16u) TFR(24u)
    x += k2; y += k0 + 2u;
    TFR(13u) TFR(15u) TFR(26u) TFR(6u)
    x += k0; y += k1 + 3u;
    TFR(17u) TFR(29u) TFR(16u) TFR(24u)
    x += k1; y += k2 + 4u;
    TFR(13u) TFR(15u) TFR(26u) TFR(6u)
    x += k2; y += k0 + 5u;
#undef TFR
    o0 = x; o1 = y;
}

// JAX partitionable-mode bits: element m uses counter (0, m), bits = o0 ^ o1.
__device__ __forceinline__ float jax_gumbel_part(uint32_t m) {
    const float TINY = 1.17549435e-38f;
    uint32_t o0, o1;
    threefry2x32(0u, 42u, 0u, m, o0, o1);
    uint32_t bits = o0 ^ o1;
    uint32_t fb = (bits >> 9) | 0x3f800000u;
    float f = __uint_as_float(fb) - 1.0f;
    float u = fmaxf(TINY, f + TINY);
    return -logf(-logf(u));
}

// ---------------- K1: QKV projections, grid (320, 3) ----------------
__global__ __launch_bounds__(256) void qkv_kernel(
    const float* __restrict__ x,
    const float* __restrict__ nq, const float* __restrict__ nk,
    const float* __restrict__ nv,
    const float* __restrict__ wq_w, const float* __restrict__ wq_b,
    const float* __restrict__ wk_w, const float* __restrict__ wk_b,
    const float* __restrict__ wv_w, const float* __restrict__ wv_b,
    float* __restrict__ qtmp, float* __restrict__ knew, float* __restrict__ vnew)
{
    const int bp = blockIdx.x;
    const int m  = blockIdx.y;
    const int d  = threadIdx.x;

    __shared__ float xs[DM];
    xs[d] = x[bp * DM + d];
    __syncthreads();

    const float* W; const float* bias; const float* noise; float* outp;
    if (m == 0)      { W = wq_w; bias = wq_b; noise = nq; outp = qtmp + (size_t)bp * SL; }
    else if (m == 1) { W = wk_w; bias = wk_b; noise = nk; outp = knew + (size_t)bp * DM; }
    else             { W = wv_w; bias = wv_b; noise = nv; outp = vnew + (size_t)bp * DM; }

    float a0 = 0.f, a1 = 0.f, a2 = 0.f, a3 = 0.f;
    #pragma unroll 4
    for (int i = 0; i < 64; ++i) {
        a0 = fmaf(xs[i],       W[(i      ) * DM + d], a0);
        a1 = fmaf(xs[i +  64], W[(i +  64) * DM + d], a1);
        a2 = fmaf(xs[i + 128], W[(i + 128) * DM + d], a2);
        a3 = fmaf(xs[i + 192], W[(i + 192) * DM + d], a3);
    }
    outp[d] = (a0 + a1) + (a2 + a3) + bias[d] + SQRT_SIGMA * noise[bp * DM + d];
}

// ---------------- K2: fused flash-decode attention chunk + identity copy-out ----
// grid (320, 4) x 256. Chunk sc covers rows [sc*128, sc*128+128).
// Streams K rows (writing rows s>t straight to K_out), computes local logits,
// local max/expsum, then streams V rows (writing s>t to V_out) accumulating the
// unnormalized z-partial. Writes logits, zpart, (m,e) to scratch for combine.
__global__ __launch_bounds__(256) void attn_chunk_kernel(
    const float* __restrict__ Kin, const float* __restrict__ Vin,
    const float* __restrict__ knew, const float* __restrict__ vnew,
    const float* __restrict__ qtmp, const int* __restrict__ t_ptr,
    float* __restrict__ Kout, float* __restrict__ Vout,
    float* __restrict__ logits, float* __restrict__ zpart,
    float* __restrict__ mstat)
{
    const int bp   = blockIdx.x;
    const int sc   = blockIdx.y;        // 0..3
    const int tid  = threadIdx.x;
    const int lane = tid & 63;
    const int wave = tid >> 6;          // 0..3
    const int t    = *t_ptr;

    __shared__ float qs[DM], ks[DM], vs[DM];
    __shared__ float att_loc[128];      // chunk logits, then unnormalized p
    __shared__ float scratch[4 * 256];
    __shared__ float redm[2], rede[2];

    if (tid < DM) {
        qs[tid] = qtmp[(size_t)bp * SL + tid];
        ks[tid] = knew[(size_t)bp * DM + tid];
        vs[tid] = vnew[(size_t)bp * DM + tid];
    }
    __syncthreads();

    const float* Kbp = Kin + (size_t)bp * SL * DM;
    const float* Vbp = Vin + (size_t)bp * SL * DM;
    float4 q4 = *(const float4*)&qs[lane * 4];
    const int s0 = sc * 128 + wave * 32;

    // ---- phase A: logits for 32 rows/wave + identity copy-out of K ----
    for (int j0 = 0; j0 < 32; j0 += 8) {
        float4 k4[8];
        #pragma unroll
        for (int u = 0; u < 8; ++u) {
            int s = s0 + j0 + u;
            k4[u] = (s == t) ? *(const float4*)&ks[lane * 4]
                             : *(const float4*)&Kbp[(size_t)s * DM + lane * 4];
        }
        #pragma unroll
        for (int u = 0; u < 8; ++u) {
            int s = s0 + j0 + u;
            if (s > t) *(float4*)(Kout + ((size_t)bp * SL + s) * DM + lane * 4) = k4[u];
            float acc = q4.x * k4[u].x + q4.y * k4[u].y + q4.z * k4[u].z + q4.w * k4[u].w;
            #pragma unroll
            for (int off = 32; off; off >>= 1) acc += __shfl_down(acc, off);
            if (lane == 0) {
                float l = acc * 0.0625f;
                att_loc[wave * 32 + j0 + u] = l;
                logits[(size_t)bp * SL + s] = l;
            }
        }
    }
    __syncthreads();

    // ---- phase B: local max + unnormalized exp + local sum (waves 0,1) ----
    float l = (tid < 128) ? att_loc[tid] : -3.402823466e+38f;
    float mm = l;
    #pragma unroll
    for (int off = 32; off; off >>= 1) mm = fmaxf(mm, __shfl_down(mm, off));
    if (tid < 128 && lane == 0) redm[wave] = mm;
    __syncthreads();
    const float m_loc = fmaxf(redm[0], redm[1]);
    float p = (tid < 128) ? expf(l - m_loc) : 0.f;
    if (tid < 128) att_loc[tid] = p;
    float e = p;
    #pragma unroll
    for (int off = 32; off; off >>= 1) e += __shfl_down(e, off);
    if (tid < 128 && lane == 0) rede[wave] = e;
    __syncthreads();
    const float e_loc = rede[0] + rede[1];

    // ---- phase C: z-partial over chunk + identity copy-out of V ----
    float4 z4 = make_float4(0.f, 0.f, 0.f, 0.f);
    for (int j0 = 0; j0 < 32; j0 += 8) {
        float4 v4[8];
        #pragma unroll
        for (int u = 0; u < 8; ++u) {
            int s = s0 + j0 + u;
            v4[u] = (s == t) ? *(const float4*)&vs[lane * 4]
                             : *(const float4*)&Vbp[(size_t)s * DM + lane * 4];
        }
        #pragma unroll
        for (int u = 0; u < 8; ++u) {
            int s = s0 + j0 + u;
            if (s > t) *(float4*)(Vout + ((size_t)bp * SL + s) * DM + lane * 4) = v4[u];
            float a = att_loc[wave * 32 + j0 + u];
            z4.x = fmaf(a, v4[u].x, z4.x);
            z4.y = fmaf(a, v4[u].y, z4.y);
            z4.z = fmaf(a, v4[u].z, z4.z);
            z4.w = fmaf(a, v4[u].w, z4.w);
        }
    }
    *(float4*)&scratch[wave * 256 + lane * 4] = z4;
    __syncthreads();
    if (tid < DM) {
        float zp = (scratch[tid] + scratch[256 + tid]) + (scratch[512 + tid] + scratch[768 + tid]);
        zpart[((size_t)bp * 4 + sc) * DM + tid] = zp;
    }
    if (tid == 0) {
        mstat[((size_t)bp * 4 + sc) * 2 + 0] = m_loc;
        mstat[((size_t)bp * 4 + sc) * 2 + 1] = e_loc;
    }
}

// ---------------- K2c: combine chunks -> attn weights + z ----------------
__global__ __launch_bounds__(256) void attn_combine_kernel(
    const float* __restrict__ logits, const float* __restrict__ zpart,
    const float* __restrict__ mstat,
    float* __restrict__ attn_out, float* __restrict__ ztmp)
{
    const int bp  = blockIdx.x;
    const int tid = threadIdx.x;

    const float* ms = mstat + (size_t)bp * 8;
    float m0 = ms[0], e0 = ms[1], m1 = ms[2], e1 = ms[3];
    float m2 = ms[4], e2 = ms[5], m3 = ms[6], e3 = ms[7];
    float gm = fmaxf(fmaxf(m0, m1), fmaxf(m2, m3));
    float f0 = expf(m0 - gm), f1 = expf(m1 - gm);
    float f2 = expf(m2 - gm), f3 = expf(m3 - gm);
    float inv = 1.0f / (e0 * f0 + e1 * f1 + e2 * f2 + e3 * f3);

    // attention weights (512)
    float l0 = logits[(size_t)bp * SL + tid];
    float l1 = logits[(size_t)bp * SL + tid + 256];
    attn_out[(size_t)bp * SL + tid]       = expf(l0 - gm) * inv;
    attn_out[(size_t)bp * SL + tid + 256] = expf(l1 - gm) * inv;

    // z (256)
    const float* zp = zpart + (size_t)bp * 4 * DM;
    float z = (zp[tid] * f0 + zp[DM + tid] * f1)
            + (zp[2 * DM + tid] * f2 + zp[3 * DM + tid] * f3);
    ztmp[(size_t)bp * DM + tid] = z * inv;
}

// ---------------- K3: zproj + LN1 + FFN + LN2, 320 x 1024 ----------------
__global__ __launch_bounds__(1024) void post_kernel(
    const float* __restrict__ x, const float* __restrict__ nz,
    const float* __restrict__ wz_w, const float* __restrict__ wz_b,
    const float* __restrict__ ln1_g, const float* __restrict__ ln1_b,
    const float* __restrict__ w1, const float* __restrict__ b1,
    const float* __restrict__ w2, const float* __restrict__ b2,
    const float* __restrict__ ln2_g, const float* __restrict__ ln2_b,
    float* __restrict__ r_out)   // holds z on entry
{
    const int bp   = blockIdx.x;
    const int tid  = threadIdx.x;
    const int lane = tid & 63;
    const int wave = tid >> 6;
    const int grp  = tid >> 8;      // 0..3
    const int qtid = tid & 255;

    __shared__ float buf[DM];       // z, then ln1-out
    __shared__ float xs[DM];
    __shared__ float hid[FF];
    __shared__ float scratch[1024];
    __shared__ float red[32];

    if (tid < DM) {
        buf[tid] = r_out[(size_t)bp * DM + tid];
        xs[tid]  = x[bp * DM + tid];
    }
    __syncthreads();

    // ---- z projection, i-split 4 ways ----
    {
        const int i0 = grp * 64;
        float a0 = 0.f, a1 = 0.f;
        #pragma unroll 4
        for (int ii = 0; ii < 32; ++ii) {
            a0 = fmaf(buf[i0 + ii],      wz_w[(i0 + ii)      * DM + qtid], a0);
            a1 = fmaf(buf[i0 + ii + 32], wz_w[(i0 + ii + 32) * DM + qtid], a1);
        }
        scratch[grp * 256 + qtid] = a0 + a1;
    }
    __syncthreads();
    float h = 0.f;
    if (tid < DM) {
        float az = (scratch[tid] + scratch[256 + tid]) + (scratch[512 + tid] + scratch[768 + tid]);
        h = az + wz_b[tid] + SQRT_SIGMA * nz[bp * DM + tid] + xs[tid];
    }

    // ---- layernorm 1 ----
    float s1 = h;
    #pragma unroll
    for (int off = 32; off; off >>= 1) s1 += __shfl_down(s1, off);
    if (lane == 0) red[wave] = s1;
    __syncthreads();
    float mu = (red[0] + red[1] + red[2] + red[3]) * (1.0f / DM);
    float dv = (tid < DM) ? (h - mu) : 0.f;
    float s2 = dv * dv;
    #pragma unroll
    for (int off = 32; off; off >>= 1) s2 += __shfl_down(s2, off);
    if (lane == 0) red[16 + wave] = s2;
    __syncthreads();
    float var = (red[16] + red[17] + red[18] + red[19]) * (1.0f / DM);
    float o = 0.f;
    __syncthreads();
    if (tid < DM) {
        o = dv * rsqrtf(var + 1e-6f) * ln1_g[tid] + ln1_b[tid];
        buf[tid] = o;
    }
    __syncthreads();

    // ---- FFN1 (256 -> 1024) ----
    {
        float h0 = 0.f, h1 = 0.f, h2 = 0.f, h3 = 0.f;
        #pragma unroll 4
        for (int i = 0; i < 64; ++i) {
            h0 = fmaf(buf[i],       w1[(i      ) * FF + tid], h0);
            h1 = fmaf(buf[i +  64], w1[(i +  64) * FF + tid], h1);
            h2 = fmaf(buf[i + 128], w1[(i + 128) * FF + tid], h2);
            h3 = fmaf(buf[i + 192], w1[(i + 192) * FF + tid], h3);
        }
        hid[tid] = fmaxf((h0 + h1) + (h2 + h3) + b1[tid], 0.f);
    }
    __syncthreads();

    // ---- FFN2 (1024 -> 256), i-split 4 ways ----
    {
        const int i0 = grp * 256;
        float a0 = 0.f, a1 = 0.f, a2 = 0.f, a3 = 0.f;
        #pragma unroll 4
        for (int ii = 0; ii < 64; ++ii) {
            a0 = fmaf(hid[i0 + ii],       w2[(i0 + ii      ) * DM + qtid], a0);
            a1 = fmaf(hid[i0 + ii +  64], w2[(i0 + ii +  64) * DM + qtid], a1);
            a2 = fmaf(hid[i0 + ii + 128], w2[(i0 + ii + 128) * DM + qtid], a2);
            a3 = fmaf(hid[i0 + ii + 192], w2[(i0 + ii + 192) * DM + qtid], a3);
        }
        scratch[grp * 256 + qtid] = (a0 + a1) + (a2 + a3);
    }
    __syncthreads();
    float rr = 0.f;
    if (tid < DM) {
        rr = (scratch[tid] + scratch[256 + tid]) + (scratch[512 + tid] + scratch[768 + tid])
           + b2[tid] + o;
    }

    // ---- layernorm 2 ----
    float t1 = rr;
    #pragma unroll
    for (int off = 32; off; off >>= 1) t1 += __shfl_down(t1, off);
    if (lane == 0) red[wave] = t1;
    __syncthreads();
    float mu2 = (red[0] + red[1] + red[2] + red[3]) * (1.0f / DM);
    float dv2 = (tid < DM) ? (rr - mu2) : 0.f;
    float t2 = dv2 * dv2;
    #pragma unroll
    for (int off = 32; off; off >>= 1) t2 += __shfl_down(t2, off);
    if (lane == 0) red[16 + wave] = t2;
    __syncthreads();
    float var2 = (red[16] + red[17] + red[18] + red[19]) * (1.0f / DM);
    if (tid < DM) {
        float rf = dv2 * rsqrtf(var2 + 1e-6f) * ln2_g[tid] + ln2_b[tid];
        r_out[(size_t)bp * DM + tid] = rf;
    }
}

// ---------------- K4: particle weights + resample indices ----------------
__global__ __launch_bounds__(320) void weights_kernel(
    const float* __restrict__ r, const float* __restrict__ y,
    const float* __restrict__ out_w, const float* __restrict__ out_b,
    float* __restrict__ w_out, int* __restrict__ i_t)
{
    const int b   = blockIdx.x;    // 0..31
    const int tid = threadIdx.x;   // 0..319
    const int p   = tid >> 5;      // 0..9
    const int j   = tid & 31;      // 0..31

    __shared__ float sred[NPART];
    __shared__ float es[NPART];
    __shared__ float pe[NPART];
    __shared__ float wsm[NPART];

    const float* rrow = r + (size_t)(b * NPART + p) * DM;
    float acc = 0.f;
    #pragma unroll 4
    for (int i = 0; i < DM; ++i) acc = fmaf(rrow[i], out_w[i * OD + j], acc);
    float pred = acc + out_b[j];
    float muv  = y[(size_t)(b * NPART + p) * OD + j] - pred;
    float s    = muv * muv;
    #pragma unroll
    for (int off = 16; off; off >>= 1) s += __shfl_down(s, off, 32);
    if (j == 0) sred[p] = s;   // log_w = -s
    __syncthreads();

    if (tid < NPART) es[tid] = expf(-sred[tid]);
    __syncthreads();
    if (tid < NPART) {
        float mx = es[0];
        #pragma unroll
        for (int i = 1; i < NPART; ++i) mx = fmaxf(mx, es[i]);
        pe[tid] = expf(es[tid] - mx);
    }
    __syncthreads();
    if (tid < NPART) {
        float sum = 0.f;
        #pragma unroll
        for (int i = 0; i < NPART; ++i) sum += pe[i];
        float wv = pe[tid] / sum;
        w_out[b * NPART + tid] = wv;
        wsm[tid] = wv;
    }
    __syncthreads();

    if (tid < NPART) {
        int pp = tid;
        int best = 0;
        float bests = -3.402823466e+38f;
        #pragma unroll
        for (int jj = 0; jj < NPART; ++jj) {
            uint32_t m = (uint32_t)(b * 100 + pp * 10 + jj);
            float score = jax_gumbel_part(m) + wsm[jj];
            if (score > bests) { bests = score; best = jj; }
        }
        i_t[b * NPART + pp] = best;
    }
}

// ---------------- K5: resample gather-copy ----------------
// y=0: V rows s<=t (L3-hot from K2), y=1: K rows s<=t, y=2: R all rows.
__global__ __launch_bounds__(256) void resample_kernel(
    const float* __restrict__ Kin, const float* __restrict__ Vin,
    const float* __restrict__ Rin,
    const float* __restrict__ knew, const float* __restrict__ vnew,
    const float* __restrict__ rnew,
    const int* __restrict__ i_t, const int* __restrict__ t_ptr,
    float* __restrict__ Kout, float* __restrict__ Vout, float* __restrict__ Rout)
{
    const int t    = *t_ptr;
    const int ysel = blockIdx.y;            // 0=V 1=K 2=R
    const int tid  = threadIdx.x;
    size_t idx  = (size_t)blockIdx.x * 256 + tid;
    int lane4 = (int)(idx & 63);            // float4 slot within row
    int row   = (int)(idx >> 6);            // 0..163839
    int bpi   = row >> 9;                   // 0..319
    int s     = row & 511;

    if (ysel != 2 && s > t) return;         // K/V identity rows done in K2

    int b     = bpi / NPART;
    int p     = bpi - b * NPART;
    int srcp  = (s <= t) ? i_t[bpi] : p;
    int src_bpi = b * NPART + srcp;

    const float* src;
    if (s == t) {
        const float* nb = (ysel == 1) ? knew : (ysel == 0) ? vnew : rnew;
        src = nb + (size_t)src_bpi * DM;
    } else {
        const float* base = (ysel == 1) ? Kin : (ysel == 0) ? Vin : Rin;
        src = base + ((size_t)src_bpi * SL + s) * DM;
    }
    float* outb = (ysel == 1) ? Kout : (ysel == 0) ? Vout : Rout;
    float4 v4 = *(const float4*)(src + (size_t)lane4 * 4);
    *(float4*)(outb + (size_t)row * DM + (size_t)lane4 * 4) = v4;
}

// ---------------- launch ----------------
extern "C" void kernel_launch(void* const* d_in, const int* in_sizes, int n_in,
                              void* d_out, int out_size, void* d_ws, size_t ws_size,
                              hipStream_t stream) {
    const float* x    = (const float*)d_in[0];
    const float* y    = (const float*)d_in[1];
    const float* Kin  = (const float*)d_in[2];
    const float* Vin  = (const float*)d_in[3];
    const float* Rin  = (const float*)d_in[4];
    const float* nq   = (const float*)d_in[5];
    const float* nk   = (const float*)d_in[6];
    const float* nv   = (const float*)d_in[7];
    const float* nz   = (const float*)d_in[8];
    const int*   tptr = (const int*)d_in[9];
    const float* wq_w = (const float*)d_in[10];
    const float* wq_b = (const float*)d_in[11];
    const float* wk_w = (const float*)d_in[12];
    const float* wk_b = (const float*)d_in[13];
    const float* wv_w = (const float*)d_in[14];
    const float* wv_b = (const float*)d_in[15];
    const float* wz_w = (const float*)d_in[16];
    const float* wz_b = (const float*)d_in[17];
    const float* ln1g = (const float*)d_in[18];
    const float* ln1b = (const float*)d_in[19];
    const float* w1   = (const float*)d_in[20];
    const float* b1   = (const float*)d_in[21];
    const float* w2   = (const float*)d_in[22];
    const float* b2   = (const float*)d_in[23];
    const float* ln2g = (const float*)d_in[24];
    const float* ln2b = (const float*)d_in[25];
    const float* outw = (const float*)d_in[26];
    const float* outb = (const float*)d_in[27];

    float* out = (float*)d_out;
    const size_t R_ELEMS    = (size_t)BP_TOT * DM;        // 81920
    const size_t ATTN_ELEMS = (size_t)BP_TOT * SL;        // 163840
    const size_t KVR_ELEMS  = (size_t)BP_TOT * SL * DM;   // 41943040
    float* r_out    = out;
    float* attn_out = out + R_ELEMS;
    float* K_out    = out + R_ELEMS + ATTN_ELEMS;
    float* V_out    = K_out + KVR_ELEMS;
    float* R_out    = V_out + KVR_ELEMS;
    float* w_out    = R_out + KVR_ELEMS;

    float* knew = (float*)d_ws;
    float* vnew = knew + R_ELEMS;
    int*   i_t  = (int*)(vnew + R_ELEMS);

    // scratch in the R_out head (dead until K5 overwrites it at the end):
    float* logits = R_out;                          // 320*512
    float* zpart  = R_out + ATTN_ELEMS;             // 320*4*256
    float* mstat  = zpart + (size_t)BP_TOT * 4 * DM; // 320*8

    // K1: q -> attn_out scratch, k/v -> ws
    qkv_kernel<<<dim3(BP_TOT, 3), 256, 0, stream>>>(
        x, nq, nk, nv, wq_w, wq_b, wk_w, wk_b, wv_w, wv_b,
        attn_out, knew, vnew);

    // K2: fused flash-decode chunks + identity copy-out of K/V rows s>t
    attn_chunk_kernel<<<dim3(BP_TOT, 4), 256, 0, stream>>>(
        Kin, Vin, knew, vnew, attn_out, tptr,
        K_out, V_out, logits, zpart, mstat);

    // K2c: combine -> attn_out weights + z (in r_out scratch)
    attn_combine_kernel<<<BP_TOT, 256, 0, stream>>>(
        logits, zpart, mstat, attn_out, r_out);

    // K3: zproj + LN1 + FFN + LN2 -> r_out
    post_kernel<<<BP_TOT, 1024, 0, stream>>>(
        x, nz, wz_w, wz_b, ln1g, ln1b, w1, b1, w2, b2, ln2g, ln2b,
        r_out);

    weights_kernel<<<BATCH, 320, 0, stream>>>(
        r_out, y, outw, outb, w_out, i_t);

    resample_kernel<<<dim3(163840 / 4, 3), 256, 0, stream>>>(
        Kin, Vin, Rin, knew, vnew, r_out, i_t, tptr,
        K_out, V_out, R_out);
}